// Round 7
// baseline (161.483 us; speedup 1.0000x reference)
//
#include <hip/hip_runtime.h>
#include <hip/hip_bf16.h>
#include <stdint.h>

#define BATCH 8192
#define NSTATE 30
#define DIN 13
#define E1 256
#define E2 128

typedef short bf16x8 __attribute__((ext_vector_type(8)));
typedef float f32x4 __attribute__((ext_vector_type(4)));
typedef float f32x16 __attribute__((ext_vector_type(16)));
typedef __bf16 bf16x2_t __attribute__((ext_vector_type(2)));

// f32 -> bf16 bits, round-to-nearest-even (native cast -> v_cvt_pk_bf16_f32)
__device__ __forceinline__ unsigned short f2b(float f) {
    return __builtin_bit_cast(unsigned short, (__bf16)f);
}
__device__ __forceinline__ float b2f(unsigned short b) {
    return __uint_as_float((unsigned)b << 16);
}
__device__ __forceinline__ unsigned pack2(float a, float b) {     // relu+pack
    bf16x2_t v = {(__bf16)fmaxf(a, 0.f), (__bf16)fmaxf(b, 0.f)};
    return __builtin_bit_cast(unsigned, v);
}
__device__ __forceinline__ unsigned pack2n(float a, float b) {    // pack only
    bf16x2_t v = {(__bf16)a, (__bf16)b};
    return __builtin_bit_cast(unsigned, v);
}

// combined conv1 weight values (derived R1, verified)
__device__ __forceinline__ float wcat_val(int k, int m, const float* relW, const float* rootW) {
    int part = k >> 7, c = k & 127, grp = m >> 5, mm = m & 31;
    int off = c * 32 + mm;
    if (part == 0) return (grp == 0) ? rootW[4096 + off] + rootW[8192 + off]
                        : (grp == 1) ? relW[off] : relW[3*4096 + off];
    if (part == 1) return (grp == 0) ? relW[1*4096 + off]
                        : (grp == 1) ? relW[6*4096 + off] : relW[5*4096 + off];
    return (grp == 0) ? relW[2*4096 + off]
         : (grp == 1) ? relW[4*4096 + off] : relW[7*4096 + off];
}
__device__ __forceinline__ float wc2_val(int k, int n, const float* relW, const float* rootW) {
    int grp = k >> 5, kk = k & 31;
    int off = kk * 128 + n;
    if (grp == 0) return rootW[4096 + off] + rootW[8192 + off];
    if (grp == 1) return relW[4096 + off];
    return relW[8192 + off];
}

// ---------------------------------------------------------------------------
// k_prep (R15, unchanged): fragment tables for mfma_f32_32x32x16_bf16 in
// k_mlpE + 16x16x32 tables for k_tail. See R15 header for the decode.
// ---------------------------------------------------------------------------
__global__ void k_prep(const float* __restrict__ c1_relW, const float* __restrict__ c1_relb,
                       const float* __restrict__ c1_rootW,
                       const float* __restrict__ c2_relW, const float* __restrict__ c2_relb,
                       const float* __restrict__ c2_rootW,
                       const float* __restrict__ wh_W0, const float* __restrict__ wh_W1,
                       const float* __restrict__ wo_W0, const float* __restrict__ wo_W1,
                       const float* __restrict__ wr_W0, const float* __restrict__ wr_W1,
                       const float* __restrict__ v_W0, const float* __restrict__ v_W1,
                       const float* __restrict__ b0h, const float* __restrict__ b0o,
                       const float* __restrict__ b0r,
                       const float* __restrict__ b1h, const float* __restrict__ b1o,
                       const float* __restrict__ b1r,
                       float* __restrict__ bcat, float* __restrict__ bc2,
                       unsigned short* __restrict__ W0b_h, unsigned short* __restrict__ W0b_o,
                       unsigned short* __restrict__ W0b_r,
                       unsigned short* __restrict__ W1f_h, unsigned short* __restrict__ W1f_o,
                       unsigned short* __restrict__ W1f_r,
                       unsigned short* __restrict__ Mf_h, unsigned short* __restrict__ Mf_o,
                       unsigned short* __restrict__ Wcatf, unsigned short* __restrict__ Wc2f,
                       unsigned short* __restrict__ vW0f, unsigned short* __restrict__ vW1f)
{
    int gid = blockIdx.x * blockDim.x + threadIdx.x;
    int gsz = gridDim.x * blockDim.x;

    for (int i = gid; i < 96; i += gsz) {
        int grp = i >> 5, mm = i & 31;
        float v;
        if (grp == 0)      v = c1_relb[32 + mm] + c1_relb[64 + mm];
        else if (grp == 1) v = c1_relb[mm] + c1_relb[128 + mm] + c1_relb[192 + mm];
        else               v = c1_relb[96 + mm] + c1_relb[160 + mm] + c1_relb[224 + mm];
        bcat[i] = v;
    }
    for (int i = gid; i < 128; i += gsz) bc2[i] = c2_relb[128 + i] + c2_relb[256 + i];

    // W0 fragments (32x32x16): 8 nt_h tiles x 64 lanes x 8 slots
    for (int i = gid; i < 4096; i += gsz) {
        int j = i & 7, l = (i >> 3) & 63, nh = i >> 9;
        int col = nh * 32 + (l & 31);
        unsigned short vh = 0, vo = 0, vr = 0;
        if (l < 32) {
            vh = (j < 7) ? f2b(wh_W0[j * 256 + col]) : f2b(b0h[col]);
            vo = (j < 7) ? f2b(wo_W0[j * 256 + col]) : f2b(b0o[col]);
            vr = (j < 6) ? f2b(wr_W0[j * 256 + col])
               : (j == 6) ? f2b(b0r[col]) : (unsigned short)0;
        }
        W0b_h[i] = vh; W0b_o[i] = vo; W0b_r[i] = vr;
    }
    // W1 fragments (32x32x16, permuted h-dim, 17th slice = b1)
    for (int i = gid; i < 34816; i += gsz) {
        int j = i & 7, l = (i >> 3) & 63, rem = i >> 9;
        int nt = rem & 3, ks = rem >> 2;
        int ecol = nt * 32 + (l & 31);
        int hh = l >> 5;
        unsigned short vh, vo, vr;
        if (ks < 16) {
            int r = (ks & 1) * 8 + j;
            int hcol = (ks >> 1) * 32 + (r & 3) + 8 * (r >> 2) + 4 * hh;
            vh = f2b(wh_W1[hcol * 128 + ecol]);
            vo = f2b(wo_W1[hcol * 128 + ecol]);
            vr = f2b(wr_W1[hcol * 128 + ecol]);
        } else {
            bool on = (l < 32) && (j == 0);
            vh = on ? f2b(b1h[ecol]) : (unsigned short)0;
            vo = on ? f2b(b1o[ecol]) : (unsigned short)0;
            vr = on ? f2b(b1r[ecol]) : (unsigned short)0;
        }
        W1f_h[i] = vh; W1f_o[i] = vo; W1f_r[i] = vr;
    }
    // Mf fragments (32x32x16, permuted e-dim)
    for (int i = gid; i < 4096; i += gsz) {
        int j = i & 7, l = (i >> 3) & 63, kt = i >> 9;
        int hh = l >> 5, s = kt & 1, r = s * 8 + j;
        int ecol = (kt >> 1) * 32 + (r & 3) + 8 * (r >> 2) + 4 * hh;
        int tcol = l & 31;
        int i0 = ecol * 32 + tcol;
        Mf_h[i] = f2b(c1_rootW[i0] + c1_rootW[4*4096 + i0] + c1_rootW[6*4096 + i0] - c1_relW[6*4096 + i0]);
        Mf_o[i] = f2b(c1_rootW[3*4096 + i0] + c1_rootW[5*4096 + i0] + c1_rootW[7*4096 + i0] - c1_relW[7*4096 + i0]);
    }
    // ---- k_tail tables (16x16x32 layout, unchanged) ----
    for (int i = gid; i < 36864; i += gsz) {
        int j = i & 7, l = (i >> 3) & 63, rem = i >> 9;
        int nt = rem % 6, ks = rem / 6;
        int k = ks * 32 + (l >> 4) * 8 + j;
        int n = nt * 16 + (l & 15);
        Wcatf[i] = f2b(wcat_val(k, n, c1_relW, c1_rootW));
    }
    for (int i = gid; i < 12288; i += gsz) {
        int j = i & 7, l = (i >> 3) & 63, rem = i >> 9;
        int nt = rem & 7, ks = rem >> 3;
        int k = ks * 32 + (l >> 4) * 8 + j;
        int n = nt * 16 + (l & 15);
        Wc2f[i] = f2b(wc2_val(k, n, c2_relW, c2_rootW));
    }
    for (int i = gid; i < 32768; i += gsz) {
        int j = i & 7, l = (i >> 3) & 63, rem = i >> 9;
        int nt = rem & 15, ks = rem >> 4;
        int k = ks * 32 + (l >> 4) * 8 + j;
        int n = nt * 16 + (l & 15);
        vW0f[i] = f2b(v_W0[k * 256 + n]);
    }
    for (int i = gid; i < 32768; i += gsz) {
        int j = i & 7, l = (i >> 3) & 63, rem = i >> 9;
        int nt = rem & 7, ks = rem >> 3;
        int k = ks * 32 + (l >> 4) * 8 + j;
        int n = nt * 16 + (l & 15);
        vW1f[i] = f2b(v_W1[k * 128 + n]);
    }
}

// ---------------------------------------------------------------------------
// mlp_blockE (R15, unchanged): 32x32x16-MFMA register-direct dataflow.
// LDS: W0s@0 8K | Mfs@8K 8K | W1s@16K 68K | ew@86016 16x4352 = 152K total.
// ---------------------------------------------------------------------------
#define SM_W0   0
#define SM_MF   8192
#define SM_W1   16384
#define SM_HS   86016
#define SM_SZ   (86016 + 16 * 16 * 136 * 2)

template<int NPB, int NODE0, int INOFF, int INDIM, bool TAIL>
__device__ __forceinline__ void mlp_blockE(
    int blkrow0, const float* __restrict__ state,
    const unsigned short* __restrict__ W0b_g,
    const unsigned short* __restrict__ W1f_g,
    const unsigned short* __restrict__ Mf_g,
    unsigned short* __restrict__ tR, float* __restrict__ sumB,
    unsigned short* __restrict__ eR, char* smem)
{
    unsigned short* W0s = (unsigned short*)(smem + SM_W0);
    unsigned short* Mfs = (unsigned short*)(smem + SM_MF);
    unsigned short* W1s = (unsigned short*)(smem + SM_W1);

    const int t = threadIdx.x;
    const int lane = t & 63;
    const int w = t >> 6;
    const int l31 = lane & 31;
    const int hi = lane >> 5;
    const int R0 = blkrow0 + w * 64;      // this wave's 64 contiguous rows
    unsigned short* ew = (unsigned short*)(smem + SM_HS) + w * (16 * 136); // [16][136]

    // ---- one-time staging (1024 threads) ----
    if (t < 512) ((uint4*)W0s)[t] = ((const uint4*)W0b_g)[t];
    if constexpr (TAIL) {
        if (t >= 512) ((uint4*)Mfs)[t - 512] = ((const uint4*)Mf_g)[t - 512];
    }
    #pragma unroll
    for (int i = 0; i < 4; ++i)
        ((uint4*)W1s)[t + 1024 * i] = ((const uint4*)W1f_g)[t + 1024 * i];
    if (t < 256) ((uint4*)W1s)[4096 + t] = ((const uint4*)W1f_g)[4096 + t];
    __syncthreads();   // the ONLY block-wide barrier

    // constant ones-fragment for the b1 bias K-slice (k-slot 0 on lo lanes)
    bf16x8 bones = {};
    if (lane < 32) bones[0] = (short)0x3F80;

    float s0 = 0.f, s1 = 0.f;
    int bcur = R0 / NPB;

    // ---- X pipeline: lanes 0..31 own rows l31; prefetch next sub ----
    float xf[INDIM];
    if (lane < 32) {
        int grow = R0 + l31;
        int b = grow / NPB;
        int n = grow - b * NPB + NODE0;
        const float* xp = state + ((size_t)b * NSTATE + n) * DIN + INOFF;
        #pragma unroll
        for (int j = 0; j < INDIM; ++j) xf[j] = xp[j];
    }

    for (int sub = 0; sub < 2; ++sub) {
        const int wrow0 = R0 + sub * 32;

        bf16x8 bx = {};
        if (lane < 32) {
            #pragma unroll
            for (int j = 0; j < INDIM; ++j) bx[j] = (short)f2b(xf[j]);
            bx[INDIM] = (short)0x3F80;   // multiplies the b0 A-slot
        }
        if (sub < 1 && lane < 32) {
            int grow = wrow0 + 32 + l31;
            int b = grow / NPB;
            int n = grow - b * NPB + NODE0;
            const float* xp = state + ((size_t)b * NSTATE + n) * DIN + INOFF;
            #pragma unroll
            for (int j = 0; j < INDIM; ++j) xf[j] = xp[j];
        }

        // ---- L1 + L2 interleaved: per h-tile nh, one 32x32 L1 MFMA makes
        // h cols 32nh..+31; pack regs 0..7 / 8..15 into the two K-slice
        // B-fragments and immediately burn them against 4 e-col tiles. ----
        f32x16 acc[4];
        #pragma unroll
        for (int nt = 0; nt < 4; ++nt) { f32x16 z = {}; acc[nt] = z; }
        #pragma unroll
        for (int nh = 0; nh < 8; ++nh) {
            bf16x8 aw0 = *(const bf16x8*)(W0s + (nh * 64 + lane) * 8);
            f32x16 z = {};
            f32x16 a1 = __builtin_amdgcn_mfma_f32_32x32x16_bf16(aw0, bx, z, 0, 0, 0);
            uint4 ua, ub;
            ua.x = pack2(a1[0], a1[1]);   ua.y = pack2(a1[2], a1[3]);
            ua.z = pack2(a1[4], a1[5]);   ua.w = pack2(a1[6], a1[7]);
            ub.x = pack2(a1[8], a1[9]);   ub.y = pack2(a1[10], a1[11]);
            ub.z = pack2(a1[12], a1[13]); ub.w = pack2(a1[14], a1[15]);
            bf16x8 bhA = __builtin_bit_cast(bf16x8, ua);
            bf16x8 bhB = __builtin_bit_cast(bf16x8, ub);
            #pragma unroll
            for (int nt = 0; nt < 4; ++nt) {
                bf16x8 aw = *(const bf16x8*)(W1s + (((2 * nh) * 4 + nt) * 64 + lane) * 8);
                acc[nt] = __builtin_amdgcn_mfma_f32_32x32x16_bf16(aw, bhA, acc[nt], 0, 0, 0);
            }
            #pragma unroll
            for (int nt = 0; nt < 4; ++nt) {
                bf16x8 aw = *(const bf16x8*)(W1s + (((2 * nh + 1) * 4 + nt) * 64 + lane) * 8);
                acc[nt] = __builtin_amdgcn_mfma_f32_32x32x16_bf16(aw, bhB, acc[nt], 0, 0, 0);
            }
        }
        // b1 bias K-slice
        #pragma unroll
        for (int nt = 0; nt < 4; ++nt) {
            bf16x8 aw = *(const bf16x8*)(W1s + ((64 + nt) * 64 + lane) * 8);
            acc[nt] = __builtin_amdgcn_mfma_f32_32x32x16_bf16(aw, bones, acc[nt], 0, 0, 0);
        }

        // relu+pack e once; feeds t-MFMA B, ew stores, eR stores
        unsigned pvu[4][8];
        #pragma unroll
        for (int nt = 0; nt < 4; ++nt)
            #pragma unroll
            for (int p = 0; p < 8; ++p)
                pvu[nt][p] = pack2(acc[nt][2 * p], acc[nt][2 * p + 1]);

        if constexpr (TAIL) {
            // t = e @ M : A=Mf (permuted e-dim), B=e from REGISTERS
            f32x16 tacc = {};
            #pragma unroll
            for (int kt = 0; kt < 8; ++kt) {
                const int nt = kt >> 1, s = kt & 1;
                uint4 ua = {pvu[nt][4 * s], pvu[nt][4 * s + 1],
                            pvu[nt][4 * s + 2], pvu[nt][4 * s + 3]};
                bf16x8 ae = __builtin_bit_cast(bf16x8, ua);
                bf16x8 bm = *(const bf16x8*)(Mfs + (kt * 64 + lane) * 8);
                tacc = __builtin_amdgcn_mfma_f32_32x32x16_bf16(bm, ae, tacc, 0, 0, 0);
            }
            // tR row-major store: lane's row = wrow0+l31; 16 t-cols per lane
            {
                unsigned short* tRrow = tR + (size_t)(wrow0 + l31) * 32 + 4 * hi;
                #pragma unroll
                for (int q = 0; q < 4; ++q) {
                    uint2 tv = {pack2n(tacc[4 * q], tacc[4 * q + 1]),
                                pack2n(tacc[4 * q + 2], tacc[4 * q + 3])};
                    *(uint2*)(tRrow + 8 * q) = tv;
                }
            }
            // ew + scan in two 16-row half-passes (preserves old scan format)
            #pragma unroll
            for (int half = 0; half < 2; ++half) {
                __asm__ __volatile__("s_waitcnt lgkmcnt(0)" ::: "memory");
                if ((l31 >> 4) == half) {
                    unsigned short* er = ew + (l31 & 15) * 136 + 4 * hi;
                    #pragma unroll
                    for (int nt = 0; nt < 4; ++nt)
                        #pragma unroll
                        for (int q = 0; q < 4; ++q)
                            *(uint2*)(er + nt * 32 + 8 * q) =
                                (uint2){pvu[nt][2 * q], pvu[nt][2 * q + 1]};
                }
                const int grow0 = wrow0 + half * 16;
                #pragma unroll
                for (int r = 0; r < 16; ++r) {
                    int b = (grow0 + r) / NPB;
                    if (b != bcur) {
                        bool interior = (bcur * NPB >= R0) && ((bcur + 1) * NPB <= R0 + 64);
                        float* dst = sumB + (size_t)bcur * 128 + 2 * lane;
                        if (interior) { dst[0] = s0; dst[1] = s1; }
                        else { atomicAdd(dst, s0); atomicAdd(dst + 1, s1); }
                        s0 = 0.f; s1 = 0.f; bcur = b;
                    }
                    unsigned v = *(const unsigned*)(ew + r * 136 + lane * 2);
                    s0 += b2f((unsigned short)v);
                    s1 += b2f((unsigned short)(v >> 16));
                }
            }
            if (sub == 1) {
                bool interior = (bcur * NPB >= R0) && ((bcur + 1) * NPB <= R0 + 64);
                float* dst = sumB + (size_t)bcur * 128 + 2 * lane;
                if (interior) { dst[0] = s0; dst[1] = s1; }
                else { atomicAdd(dst, s0); atomicAdd(dst + 1, s1); }
            }
        } else {
            // root: row-major global store eR[row][n]; lane row = wrow0+l31
            unsigned short* eRrow = eR + (size_t)(wrow0 + l31) * 128 + 4 * hi;
            #pragma unroll
            for (int nt = 0; nt < 4; ++nt)
                #pragma unroll
                for (int q = 0; q < 4; ++q)
                    *(uint2*)(eRrow + nt * 32 + 8 * q) =
                        (uint2){pvu[nt][2 * q], pvu[nt][2 * q + 1]};
        }
        __asm__ __volatile__("" ::: "memory");   // keep iteration LDS order
    }
}

__global__ __launch_bounds__(1024, 1) void k_mlpE(
    const float* __restrict__ state,
    const unsigned short* __restrict__ W0b_h,
    const unsigned short* __restrict__ W1f_h,
    const unsigned short* __restrict__ Mf_h, unsigned short* __restrict__ tR_h,
    float* __restrict__ shB,
    const unsigned short* __restrict__ W0b_o,
    const unsigned short* __restrict__ W1f_o,
    const unsigned short* __restrict__ Mf_o, unsigned short* __restrict__ tR_o,
    float* __restrict__ soB,
    const unsigned short* __restrict__ W0b_r,
    const unsigned short* __restrict__ W1f_r,
    unsigned short* __restrict__ eR)
{
    __shared__ __align__(16) char smem[SM_SZ];
    int bid = blockIdx.x;
    if (bid < 160)
        mlp_blockE<20, 0, 6, 7, true>(bid * 1024, state, W0b_h, W1f_h,
                                      Mf_h, tR_h, shB, nullptr, smem);
    else if (bid < 240)
        mlp_blockE<10, 20, 6, 7, true>((bid - 160) * 1024, state, W0b_o, W1f_o,
                                       Mf_o, tR_o, soB, nullptr, smem);
    else
        mlp_blockE<1, 0, 0, 6, false>((bid - 240) * 1024, state, W0b_r, W1f_r,
                                      nullptr, nullptr, nullptr, eR, smem);
}

// ---------------------------------------------------------------------------
// k_tail (R17 = R16 + full LDS init): 8 b's per block x 1024 blocks ->
// 4 blocks/CU (16 waves/CU) to hide the 7-phase barrier-chain latency.
// Rows 8-15 of all block-local tiles are now FULLY ZEROED in phase 1 (R16
// left cols 128..383 uninitialized -- benign but removed for certainty).
// All global reads/writes guarded to b<8. LDS 33KB x 4 = 132KB/CU.
// ---------------------------------------------------------------------------
__global__ __launch_bounds__(256, 4) void k_tail(
    const unsigned short* __restrict__ eR,
    const float* __restrict__ shB, const float* __restrict__ soB,
    const unsigned short* __restrict__ tR_h, const unsigned short* __restrict__ tR_o,
    const unsigned short* __restrict__ Wcatf, const float* __restrict__ bcat,
    const unsigned short* __restrict__ Wc2f, const float* __restrict__ bc2,
    const unsigned short* __restrict__ vW0f, const float* __restrict__ vb0,
    const unsigned short* __restrict__ vW1f, const float* __restrict__ vb1,
    const float* __restrict__ vW2, const float* __restrict__ vb2,
    float* __restrict__ out)
{
    __shared__ __align__(16) char sm[33024];
    unsigned short* Ub  = (unsigned short*)(sm);          // [16][400]
    unsigned short* V1b = (unsigned short*)(sm);          // alias  [16][264]
    unsigned short* Vb  = (unsigned short*)(sm + 12800);  // [16][104]
    float* chL          = (float*)(sm + 16128);           // [16][32]
    float* coL          = (float*)(sm + 18176);           // [16][32]
    unsigned short* Hb  = (unsigned short*)(sm + 20224);  // [16][136]
    float* V2b          = (float*)(sm + 24576);           // [16][132]

    const int t = threadIdx.x, lane = t & 63, w = t >> 6;
    const int l15 = lane & 15, quad = lane >> 4;
    const int b0 = blockIdx.x * 8;
    const int rowb = quad * 4;

    // ---- phase 1: stage U = [er | sh | so] for b 0..7; rows 8..15 zero ----
    {
        int b = t >> 4, q = t & 15;
        uint4 v = {0u, 0u, 0u, 0u};
        if (b < 8) v = ((const uint4*)(eR + (size_t)(b0 + b) * 128))[q];
        ((uint4*)(Ub + b * 400))[q] = v;
    }
    #pragma unroll
    for (int rep = 0; rep < 4; ++rep) {
        int idx = t + rep * 256;              // 1024 slots = 16 b x 64 float4
        int b = idx >> 6, q = idx & 63;
        uint2 pv = {0u, 0u};
        if (b < 8) {
            float4 v = (q < 32)
                ? *(const float4*)(shB + (size_t)(b0 + b) * 128 + q * 4)
                : *(const float4*)(soB + (size_t)(b0 + b) * 128 + (q - 32) * 4);
            pv = (uint2){pack2n(v.x, v.y), pack2n(v.z, v.w)};
        }
        *(uint2*)(Ub + b * 400 + 128 + q * 4) = pv;
    }
    __syncthreads();

    // ---- phase 2: U-MFMA (unswapped, verified): xr / ch / co ----
    for (int nt = w; nt < 6; nt += 4) {
        float bias = bcat[nt * 16 + l15];
        f32x4 acc = {bias, bias, bias, bias};
        #pragma unroll
        for (int ks = 0; ks < 12; ++ks) {
            bf16x8 a = *(const bf16x8*)(Ub + l15 * 400 + ks * 32 + quad * 8);
            bf16x8 bw = *(const bf16x8*)(Wcatf + ((ks * 6 + nt) * 64 + lane) * 8);
            acc = __builtin_amdgcn_mfma_f32_16x16x32_bf16(a, bw, acc, 0, 0, 0);
        }
        int n = nt * 16 + l15;
        #pragma unroll
        for (int reg = 0; reg < 4; ++reg) {
            float v = acc[reg];
            int b = rowb + reg;
            if (n < 32)      Vb[b * 104 + n] = f2b(fmaxf(v, 0.f));
            else if (n < 64) chL[b * 32 + (n - 32)] = v;
            else             coL[b * 32 + (n - 64)] = v;
        }
    }
    __syncthreads();

    // ---- phase 3: t-scan (row-major tR, coalesced) -> s2h, s2o; b<8 ----
    {
        int b = t >> 5, m = t & 31;           // 256 threads = 8 b x 32 m
        float ch = chL[b * 32 + m];
        const unsigned short* p = tR_h + (size_t)(b0 + b) * 20 * 32 + m;
        float s = 0.f;
        #pragma unroll
        for (int n = 0; n < 20; ++n) s += fmaxf(ch + b2f(p[n * 32]), 0.f);
        Vb[b * 104 + 32 + m] = f2b(s);
        float co = coL[b * 32 + m];
        const unsigned short* p2 = tR_o + (size_t)(b0 + b) * 10 * 32 + m;
        float s2 = 0.f;
        #pragma unroll
        for (int n = 0; n < 10; ++n) s2 += fmaxf(co + b2f(p2[n * 32]), 0.f);
        Vb[b * 104 + 64 + m] = f2b(s2);
    }
    __syncthreads();

    // ---- phase 4: c2 (N=128, 2 nt per wave) ----
    {
        f32x4 acc[2];
        #pragma unroll
        for (int q = 0; q < 2; ++q) {
            int nt = w + q * 4;
            float bias = bc2[nt * 16 + l15];
            acc[q] = (f32x4){bias, bias, bias, bias};
        }
        #pragma unroll
        for (int ks = 0; ks < 3; ++ks) {
            bf16x8 a = *(const bf16x8*)(Vb + l15 * 104 + ks * 32 + quad * 8);
            #pragma unroll
            for (int q = 0; q < 2; ++q) {
                int nt = w + q * 4;
                bf16x8 bw = *(const bf16x8*)(Wc2f + ((ks * 8 + nt) * 64 + lane) * 8);
                acc[q] = __builtin_amdgcn_mfma_f32_16x16x32_bf16(a, bw, acc[q], 0, 0, 0);
            }
        }
        #pragma unroll
        for (int q = 0; q < 2; ++q) {
            int nt = w + q * 4;
            #pragma unroll
            for (int reg = 0; reg < 4; ++reg)
                Hb[(rowb + reg) * 136 + nt * 16 + l15] = f2b(fmaxf(acc[q][reg], 0.f));
        }
    }
    __syncthreads();

    // ---- phase 5: v1 (N=256, 4 nt per wave; V1b aliases dead Ub) ----
    {
        f32x4 acc[4];
        #pragma unroll
        for (int q = 0; q < 4; ++q) {
            int nt = w + q * 4;
            float bias = vb0[nt * 16 + l15];
            acc[q] = (f32x4){bias, bias, bias, bias};
        }
        #pragma unroll
        for (int ks = 0; ks < 4; ++ks) {
            bf16x8 a = *(const bf16x8*)(Hb + l15 * 136 + ks * 32 + quad * 8);
            #pragma unroll
            for (int q = 0; q < 4; ++q) {
                int nt = w + q * 4;
                bf16x8 bw = *(const bf16x8*)(vW0f + ((ks * 16 + nt) * 64 + lane) * 8);
                acc[q] = __builtin_amdgcn_mfma_f32_16x16x32_bf16(a, bw, acc[q], 0, 0, 0);
            }
        }
        __syncthreads();   // Ub reads (phase-2 done long ago) -> safe; order vs writes
        #pragma unroll
        for (int q = 0; q < 4; ++q) {
            int nt = w + q * 4;
            #pragma unroll
            for (int reg = 0; reg < 4; ++reg)
                V1b[(rowb + reg) * 264 + nt * 16 + l15] = f2b(fmaxf(acc[q][reg], 0.f));
        }
    }
    __syncthreads();

    // ---- phase 6: v2 (N=128, 2 nt per wave) ----
    {
        f32x4 acc[2];
        #pragma unroll
        for (int q = 0; q < 2; ++q) {
            int nt = w + q * 4;
            float bias = vb1[nt * 16 + l15];
            acc[q] = (f32x4){bias, bias, bias, bias};
        }
        #pragma unroll
        for (int ks = 0; ks < 8; ++ks) {
            bf16x8 a = *(const bf16x8*)(V1b + l15 * 264 + ks * 32 + quad * 8);
            #pragma unroll
            for (int q = 0; q < 2; ++q) {
                int nt = w + q * 4;
                bf16x8 bw = *(const bf16x8*)(vW1f + ((ks * 8 + nt) * 64 + lane) * 8);
                acc[q] = __builtin_amdgcn_mfma_f32_16x16x32_bf16(a, bw, acc[q], 0, 0, 0);
            }
        }
        #pragma unroll
        for (int q = 0; q < 2; ++q) {
            int nt = w + q * 4;
            #pragma unroll
            for (int reg = 0; reg < 4; ++reg)
                V2b[(rowb + reg) * 132 + nt * 16 + l15] = fmaxf(acc[q][reg], 0.f);
        }
    }
    __syncthreads();

    // ---- phase 7: v3, 8 threads per b (b<8) + shuffle reduce ----
    if (t < 64) {
        int b = t >> 3, j = t & 7;
        float v = 0.f;
        #pragma unroll
        for (int k = 0; k < 16; ++k)
            v = fmaf(V2b[b * 132 + j * 16 + k], vW2[j * 16 + k], v);
        v += __shfl_down(v, 4, 8);
        v += __shfl_down(v, 2, 8);
        v += __shfl_down(v, 1, 8);
        if (j == 0) out[b0 + b] = v + vb2[0];
    }
}

// ---------------------------------------------------------------------------
extern "C" void kernel_launch(void* const* d_in, const int* in_sizes, int n_in,
                              void* d_out, int out_size, void* d_ws, size_t ws_size,
                              hipStream_t stream)
{
    const float* state   = (const float*)d_in[0];
    const float* wr_W0   = (const float*)d_in[2];
    const float* wr_b0   = (const float*)d_in[3];
    const float* wr_W1   = (const float*)d_in[4];
    const float* wr_b1   = (const float*)d_in[5];
    const float* wh_W0   = (const float*)d_in[6];
    const float* wh_b0   = (const float*)d_in[7];
    const float* wh_W1   = (const float*)d_in[8];
    const float* wh_b1   = (const float*)d_in[9];
    const float* wo_W0   = (const float*)d_in[10];
    const float* wo_b0   = (const float*)d_in[11];
    const float* wo_W1   = (const float*)d_in[12];
    const float* wo_b1   = (const float*)d_in[13];
    const float* c1_relW = (const float*)d_in[14];
    const float* c1_relb = (const float*)d_in[15];
    const float* c1_rootW= (const float*)d_in[16];
    const float* c2_relW = (const float*)d_in[17];
    const float* c2_relb = (const float*)d_in[18];
    const float* c2_rootW= (const float*)d_in[19];
    const float* v_W0    = (const float*)d_in[20];
    const float* v_b0    = (const float*)d_in[21];
    const float* v_W1    = (const float*)d_in[22];
    const float* v_b1    = (const float*)d_in[23];
    const float* v_W2    = (const float*)d_in[24];
    const float* v_b2    = (const float*)d_in[25];

    char* ws = (char*)d_ws;
    size_t off = 0;
    auto alloc = [&](size_t bytes) -> char* {
        char* p = ws + off;
        off = (off + bytes + 255) & ~(size_t)255;
        return p;
    };
    float* shB  = (float*)alloc((size_t)BATCH * 128 * 4);          // b-major sums
    float* soB  = (float*)alloc((size_t)BATCH * 128 * 4);          // contiguous with shB
    unsigned short* tR_h = (unsigned short*)alloc((size_t)163840 * 32 * 2);  // row-major
    unsigned short* tR_o = (unsigned short*)alloc((size_t)81920 * 32 * 2);   // row-major
    unsigned short* eR   = (unsigned short*)alloc((size_t)BATCH * 128 * 2);
    float* bcat = (float*)alloc(96 * 4);
    float* bc2  = (float*)alloc(128 * 4);
    unsigned short* W0b_h = (unsigned short*)alloc(4096 * 2);
    unsigned short* W0b_o = (unsigned short*)alloc(4096 * 2);
    unsigned short* W0b_r = (unsigned short*)alloc(4096 * 2);
    unsigned short* W1f_h = (unsigned short*)alloc(34816 * 2);
    unsigned short* W1f_o = (unsigned short*)alloc(34816 * 2);
    unsigned short* W1f_r = (unsigned short*)alloc(34816 * 2);
    unsigned short* Mf_h  = (unsigned short*)alloc(4096 * 2);
    unsigned short* Mf_o  = (unsigned short*)alloc(4096 * 2);
    unsigned short* Wcatf = (unsigned short*)alloc(36864 * 2);
    unsigned short* Wc2f  = (unsigned short*)alloc(12288 * 2);
    unsigned short* vW0f  = (unsigned short*)alloc(32768 * 2);
    unsigned short* vW1f  = (unsigned short*)alloc(32768 * 2);
    (void)ws_size; (void)in_sizes; (void)n_in; (void)out_size;

    hipMemsetAsync(shB, 0, (size_t)2 * BATCH * 128 * 4, stream);

    k_prep<<<256, 256, 0, stream>>>(c1_relW, c1_relb, c1_rootW, c2_relW, c2_relb, c2_rootW,
                                    wh_W0, wh_W1, wo_W0, wo_W1, wr_W0, wr_W1, v_W0, v_W1,
                                    wh_b0, wo_b0, wr_b0, wh_b1, wo_b1, wr_b1,
                                    bcat, bc2, W0b_h, W0b_o, W0b_r, W1f_h, W1f_o, W1f_r,
                                    Mf_h, Mf_o, Wcatf, Wc2f, vW0f, vW1f);

    k_mlpE<<<248, 1024, 0, stream>>>(state,
                                     W0b_h, W1f_h, Mf_h, tR_h, shB,
                                     W0b_o, W1f_o, Mf_o, tR_o, soB,
                                     W0b_r, W1f_r, eR);

    k_tail<<<1024, 256, 0, stream>>>(eR, shB, soB, tR_h, tR_o,
                                     Wcatf, bcat, Wc2f, bc2, vW0f, v_b0, vW1f, v_b1,
                                     v_W2, v_b2, (float*)d_out);
}

// Round 8
// 158.364 us; speedup vs baseline: 1.0197x; 1.0197x over previous
//
#include <hip/hip_runtime.h>
#include <hip/hip_bf16.h>
#include <stdint.h>

#define BATCH 8192
#define NSTATE 30
#define DIN 13
#define E1 256
#define E2 128

typedef short bf16x8 __attribute__((ext_vector_type(8)));
typedef float f32x4 __attribute__((ext_vector_type(4)));
typedef float f32x16 __attribute__((ext_vector_type(16)));
typedef __bf16 bf16x2_t __attribute__((ext_vector_type(2)));

// f32 -> bf16 bits, round-to-nearest-even (native cast -> v_cvt_pk_bf16_f32)
__device__ __forceinline__ unsigned short f2b(float f) {
    return __builtin_bit_cast(unsigned short, (__bf16)f);
}
__device__ __forceinline__ float b2f(unsigned short b) {
    return __uint_as_float((unsigned)b << 16);
}
__device__ __forceinline__ unsigned pack2(float a, float b) {     // relu+pack
    bf16x2_t v = {(__bf16)fmaxf(a, 0.f), (__bf16)fmaxf(b, 0.f)};
    return __builtin_bit_cast(unsigned, v);
}
__device__ __forceinline__ unsigned pack2n(float a, float b) {    // pack only
    bf16x2_t v = {(__bf16)a, (__bf16)b};
    return __builtin_bit_cast(unsigned, v);
}

// combined conv1 weight values (derived R1, verified)
__device__ __forceinline__ float wcat_val(int k, int m, const float* relW, const float* rootW) {
    int part = k >> 7, c = k & 127, grp = m >> 5, mm = m & 31;
    int off = c * 32 + mm;
    if (part == 0) return (grp == 0) ? rootW[4096 + off] + rootW[8192 + off]
                        : (grp == 1) ? relW[off] : relW[3*4096 + off];
    if (part == 1) return (grp == 0) ? relW[1*4096 + off]
                        : (grp == 1) ? relW[6*4096 + off] : relW[5*4096 + off];
    return (grp == 0) ? relW[2*4096 + off]
         : (grp == 1) ? relW[4*4096 + off] : relW[7*4096 + off];
}
__device__ __forceinline__ float wc2_val(int k, int n, const float* relW, const float* rootW) {
    int grp = k >> 5, kk = k & 31;
    int off = kk * 128 + n;
    if (grp == 0) return rootW[4096 + off] + rootW[8192 + off];
    if (grp == 1) return relW[4096 + off];
    return relW[8192 + off];
}

// ---------------------------------------------------------------------------
// k_prep (R15, unchanged): fragment tables for mfma_f32_32x32x16_bf16 in
// k_mlpE + 16x16x32 tables for k_tail. See R15 header for the decode.
// ---------------------------------------------------------------------------
__global__ void k_prep(const float* __restrict__ c1_relW, const float* __restrict__ c1_relb,
                       const float* __restrict__ c1_rootW,
                       const float* __restrict__ c2_relW, const float* __restrict__ c2_relb,
                       const float* __restrict__ c2_rootW,
                       const float* __restrict__ wh_W0, const float* __restrict__ wh_W1,
                       const float* __restrict__ wo_W0, const float* __restrict__ wo_W1,
                       const float* __restrict__ wr_W0, const float* __restrict__ wr_W1,
                       const float* __restrict__ v_W0, const float* __restrict__ v_W1,
                       const float* __restrict__ b0h, const float* __restrict__ b0o,
                       const float* __restrict__ b0r,
                       const float* __restrict__ b1h, const float* __restrict__ b1o,
                       const float* __restrict__ b1r,
                       float* __restrict__ bcat, float* __restrict__ bc2,
                       unsigned short* __restrict__ W0b_h, unsigned short* __restrict__ W0b_o,
                       unsigned short* __restrict__ W0b_r,
                       unsigned short* __restrict__ W1f_h, unsigned short* __restrict__ W1f_o,
                       unsigned short* __restrict__ W1f_r,
                       unsigned short* __restrict__ Mf_h, unsigned short* __restrict__ Mf_o,
                       unsigned short* __restrict__ Wcatf, unsigned short* __restrict__ Wc2f,
                       unsigned short* __restrict__ vW0f, unsigned short* __restrict__ vW1f)
{
    int gid = blockIdx.x * blockDim.x + threadIdx.x;
    int gsz = gridDim.x * blockDim.x;

    for (int i = gid; i < 96; i += gsz) {
        int grp = i >> 5, mm = i & 31;
        float v;
        if (grp == 0)      v = c1_relb[32 + mm] + c1_relb[64 + mm];
        else if (grp == 1) v = c1_relb[mm] + c1_relb[128 + mm] + c1_relb[192 + mm];
        else               v = c1_relb[96 + mm] + c1_relb[160 + mm] + c1_relb[224 + mm];
        bcat[i] = v;
    }
    for (int i = gid; i < 128; i += gsz) bc2[i] = c2_relb[128 + i] + c2_relb[256 + i];

    // W0 fragments (32x32x16): 8 nt_h tiles x 64 lanes x 8 slots
    for (int i = gid; i < 4096; i += gsz) {
        int j = i & 7, l = (i >> 3) & 63, nh = i >> 9;
        int col = nh * 32 + (l & 31);
        unsigned short vh = 0, vo = 0, vr = 0;
        if (l < 32) {
            vh = (j < 7) ? f2b(wh_W0[j * 256 + col]) : f2b(b0h[col]);
            vo = (j < 7) ? f2b(wo_W0[j * 256 + col]) : f2b(b0o[col]);
            vr = (j < 6) ? f2b(wr_W0[j * 256 + col])
               : (j == 6) ? f2b(b0r[col]) : (unsigned short)0;
        }
        W0b_h[i] = vh; W0b_o[i] = vo; W0b_r[i] = vr;
    }
    // W1 fragments (32x32x16, permuted h-dim, 17th slice = b1)
    for (int i = gid; i < 34816; i += gsz) {
        int j = i & 7, l = (i >> 3) & 63, rem = i >> 9;
        int nt = rem & 3, ks = rem >> 2;
        int ecol = nt * 32 + (l & 31);
        int hh = l >> 5;
        unsigned short vh, vo, vr;
        if (ks < 16) {
            int r = (ks & 1) * 8 + j;
            int hcol = (ks >> 1) * 32 + (r & 3) + 8 * (r >> 2) + 4 * hh;
            vh = f2b(wh_W1[hcol * 128 + ecol]);
            vo = f2b(wo_W1[hcol * 128 + ecol]);
            vr = f2b(wr_W1[hcol * 128 + ecol]);
        } else {
            bool on = (l < 32) && (j == 0);
            vh = on ? f2b(b1h[ecol]) : (unsigned short)0;
            vo = on ? f2b(b1o[ecol]) : (unsigned short)0;
            vr = on ? f2b(b1r[ecol]) : (unsigned short)0;
        }
        W1f_h[i] = vh; W1f_o[i] = vo; W1f_r[i] = vr;
    }
    // Mf fragments (32x32x16, permuted e-dim)
    for (int i = gid; i < 4096; i += gsz) {
        int j = i & 7, l = (i >> 3) & 63, kt = i >> 9;
        int hh = l >> 5, s = kt & 1, r = s * 8 + j;
        int ecol = (kt >> 1) * 32 + (r & 3) + 8 * (r >> 2) + 4 * hh;
        int tcol = l & 31;
        int i0 = ecol * 32 + tcol;
        Mf_h[i] = f2b(c1_rootW[i0] + c1_rootW[4*4096 + i0] + c1_rootW[6*4096 + i0] - c1_relW[6*4096 + i0]);
        Mf_o[i] = f2b(c1_rootW[3*4096 + i0] + c1_rootW[5*4096 + i0] + c1_rootW[7*4096 + i0] - c1_relW[7*4096 + i0]);
    }
    // ---- k_tail tables (16x16x32 layout, unchanged) ----
    for (int i = gid; i < 36864; i += gsz) {
        int j = i & 7, l = (i >> 3) & 63, rem = i >> 9;
        int nt = rem % 6, ks = rem / 6;
        int k = ks * 32 + (l >> 4) * 8 + j;
        int n = nt * 16 + (l & 15);
        Wcatf[i] = f2b(wcat_val(k, n, c1_relW, c1_rootW));
    }
    for (int i = gid; i < 12288; i += gsz) {
        int j = i & 7, l = (i >> 3) & 63, rem = i >> 9;
        int nt = rem & 7, ks = rem >> 3;
        int k = ks * 32 + (l >> 4) * 8 + j;
        int n = nt * 16 + (l & 15);
        Wc2f[i] = f2b(wc2_val(k, n, c2_relW, c2_rootW));
    }
    for (int i = gid; i < 32768; i += gsz) {
        int j = i & 7, l = (i >> 3) & 63, rem = i >> 9;
        int nt = rem & 15, ks = rem >> 4;
        int k = ks * 32 + (l >> 4) * 8 + j;
        int n = nt * 16 + (l & 15);
        vW0f[i] = f2b(v_W0[k * 256 + n]);
    }
    for (int i = gid; i < 32768; i += gsz) {
        int j = i & 7, l = (i >> 3) & 63, rem = i >> 9;
        int nt = rem & 7, ks = rem >> 3;
        int k = ks * 32 + (l >> 4) * 8 + j;
        int n = nt * 16 + (l & 15);
        vW1f[i] = f2b(v_W1[k * 128 + n]);
    }
}

// ---------------------------------------------------------------------------
// mlp_blockE (R15, unchanged): 32x32x16-MFMA register-direct dataflow.
// LDS: W0s@0 8K | Mfs@8K 8K | W1s@16K 68K | ew@86016 16x4352 = 152K total.
// ---------------------------------------------------------------------------
#define SM_W0   0
#define SM_MF   8192
#define SM_W1   16384
#define SM_HS   86016
#define SM_SZ   (86016 + 16 * 16 * 136 * 2)

template<int NPB, int NODE0, int INOFF, int INDIM, bool TAIL>
__device__ __forceinline__ void mlp_blockE(
    int blkrow0, const float* __restrict__ state,
    const unsigned short* __restrict__ W0b_g,
    const unsigned short* __restrict__ W1f_g,
    const unsigned short* __restrict__ Mf_g,
    unsigned short* __restrict__ tR, float* __restrict__ sumB,
    unsigned short* __restrict__ eR, char* smem)
{
    unsigned short* W0s = (unsigned short*)(smem + SM_W0);
    unsigned short* Mfs = (unsigned short*)(smem + SM_MF);
    unsigned short* W1s = (unsigned short*)(smem + SM_W1);

    const int t = threadIdx.x;
    const int lane = t & 63;
    const int w = t >> 6;
    const int l31 = lane & 31;
    const int hi = lane >> 5;
    const int R0 = blkrow0 + w * 64;      // this wave's 64 contiguous rows
    unsigned short* ew = (unsigned short*)(smem + SM_HS) + w * (16 * 136); // [16][136]

    // ---- one-time staging (1024 threads) ----
    if (t < 512) ((uint4*)W0s)[t] = ((const uint4*)W0b_g)[t];
    if constexpr (TAIL) {
        if (t >= 512) ((uint4*)Mfs)[t - 512] = ((const uint4*)Mf_g)[t - 512];
    }
    #pragma unroll
    for (int i = 0; i < 4; ++i)
        ((uint4*)W1s)[t + 1024 * i] = ((const uint4*)W1f_g)[t + 1024 * i];
    if (t < 256) ((uint4*)W1s)[4096 + t] = ((const uint4*)W1f_g)[4096 + t];
    __syncthreads();   // the ONLY block-wide barrier

    // constant ones-fragment for the b1 bias K-slice (k-slot 0 on lo lanes)
    bf16x8 bones = {};
    if (lane < 32) bones[0] = (short)0x3F80;

    float s0 = 0.f, s1 = 0.f;
    int bcur = R0 / NPB;

    // ---- X pipeline: lanes 0..31 own rows l31; prefetch next sub ----
    float xf[INDIM];
    if (lane < 32) {
        int grow = R0 + l31;
        int b = grow / NPB;
        int n = grow - b * NPB + NODE0;
        const float* xp = state + ((size_t)b * NSTATE + n) * DIN + INOFF;
        #pragma unroll
        for (int j = 0; j < INDIM; ++j) xf[j] = xp[j];
    }

    for (int sub = 0; sub < 2; ++sub) {
        const int wrow0 = R0 + sub * 32;

        bf16x8 bx = {};
        if (lane < 32) {
            #pragma unroll
            for (int j = 0; j < INDIM; ++j) bx[j] = (short)f2b(xf[j]);
            bx[INDIM] = (short)0x3F80;   // multiplies the b0 A-slot
        }
        if (sub < 1 && lane < 32) {
            int grow = wrow0 + 32 + l31;
            int b = grow / NPB;
            int n = grow - b * NPB + NODE0;
            const float* xp = state + ((size_t)b * NSTATE + n) * DIN + INOFF;
            #pragma unroll
            for (int j = 0; j < INDIM; ++j) xf[j] = xp[j];
        }

        // ---- L1 + L2 interleaved: per h-tile nh, one 32x32 L1 MFMA makes
        // h cols 32nh..+31; pack regs 0..7 / 8..15 into the two K-slice
        // B-fragments and immediately burn them against 4 e-col tiles. ----
        f32x16 acc[4];
        #pragma unroll
        for (int nt = 0; nt < 4; ++nt) { f32x16 z = {}; acc[nt] = z; }
        #pragma unroll
        for (int nh = 0; nh < 8; ++nh) {
            bf16x8 aw0 = *(const bf16x8*)(W0s + (nh * 64 + lane) * 8);
            f32x16 z = {};
            f32x16 a1 = __builtin_amdgcn_mfma_f32_32x32x16_bf16(aw0, bx, z, 0, 0, 0);
            uint4 ua, ub;
            ua.x = pack2(a1[0], a1[1]);   ua.y = pack2(a1[2], a1[3]);
            ua.z = pack2(a1[4], a1[5]);   ua.w = pack2(a1[6], a1[7]);
            ub.x = pack2(a1[8], a1[9]);   ub.y = pack2(a1[10], a1[11]);
            ub.z = pack2(a1[12], a1[13]); ub.w = pack2(a1[14], a1[15]);
            bf16x8 bhA = __builtin_bit_cast(bf16x8, ua);
            bf16x8 bhB = __builtin_bit_cast(bf16x8, ub);
            #pragma unroll
            for (int nt = 0; nt < 4; ++nt) {
                bf16x8 aw = *(const bf16x8*)(W1s + (((2 * nh) * 4 + nt) * 64 + lane) * 8);
                acc[nt] = __builtin_amdgcn_mfma_f32_32x32x16_bf16(aw, bhA, acc[nt], 0, 0, 0);
            }
            #pragma unroll
            for (int nt = 0; nt < 4; ++nt) {
                bf16x8 aw = *(const bf16x8*)(W1s + (((2 * nh + 1) * 4 + nt) * 64 + lane) * 8);
                acc[nt] = __builtin_amdgcn_mfma_f32_32x32x16_bf16(aw, bhB, acc[nt], 0, 0, 0);
            }
        }
        // b1 bias K-slice
        #pragma unroll
        for (int nt = 0; nt < 4; ++nt) {
            bf16x8 aw = *(const bf16x8*)(W1s + ((64 + nt) * 64 + lane) * 8);
            acc[nt] = __builtin_amdgcn_mfma_f32_32x32x16_bf16(aw, bones, acc[nt], 0, 0, 0);
        }

        // relu+pack e once; feeds t-MFMA B, ew stores, eR stores
        unsigned pvu[4][8];
        #pragma unroll
        for (int nt = 0; nt < 4; ++nt)
            #pragma unroll
            for (int p = 0; p < 8; ++p)
                pvu[nt][p] = pack2(acc[nt][2 * p], acc[nt][2 * p + 1]);

        if constexpr (TAIL) {
            // t = e @ M : A=Mf (permuted e-dim), B=e from REGISTERS
            f32x16 tacc = {};
            #pragma unroll
            for (int kt = 0; kt < 8; ++kt) {
                const int nt = kt >> 1, s = kt & 1;
                uint4 ua = {pvu[nt][4 * s], pvu[nt][4 * s + 1],
                            pvu[nt][4 * s + 2], pvu[nt][4 * s + 3]};
                bf16x8 ae = __builtin_bit_cast(bf16x8, ua);
                bf16x8 bm = *(const bf16x8*)(Mfs + (kt * 64 + lane) * 8);
                tacc = __builtin_amdgcn_mfma_f32_32x32x16_bf16(bm, ae, tacc, 0, 0, 0);
            }
            // tR row-major store: lane's row = wrow0+l31; 16 t-cols per lane
            {
                unsigned short* tRrow = tR + (size_t)(wrow0 + l31) * 32 + 4 * hi;
                #pragma unroll
                for (int q = 0; q < 4; ++q) {
                    uint2 tv = {pack2n(tacc[4 * q], tacc[4 * q + 1]),
                                pack2n(tacc[4 * q + 2], tacc[4 * q + 3])};
                    *(uint2*)(tRrow + 8 * q) = tv;
                }
            }
            // ew + scan in two 16-row half-passes (preserves old scan format)
            #pragma unroll
            for (int half = 0; half < 2; ++half) {
                __asm__ __volatile__("s_waitcnt lgkmcnt(0)" ::: "memory");
                if ((l31 >> 4) == half) {
                    unsigned short* er = ew + (l31 & 15) * 136 + 4 * hi;
                    #pragma unroll
                    for (int nt = 0; nt < 4; ++nt)
                        #pragma unroll
                        for (int q = 0; q < 4; ++q)
                            *(uint2*)(er + nt * 32 + 8 * q) =
                                (uint2){pvu[nt][2 * q], pvu[nt][2 * q + 1]};
                }
                const int grow0 = wrow0 + half * 16;
                #pragma unroll
                for (int r = 0; r < 16; ++r) {
                    int b = (grow0 + r) / NPB;
                    if (b != bcur) {
                        bool interior = (bcur * NPB >= R0) && ((bcur + 1) * NPB <= R0 + 64);
                        float* dst = sumB + (size_t)bcur * 128 + 2 * lane;
                        if (interior) { dst[0] = s0; dst[1] = s1; }
                        else { atomicAdd(dst, s0); atomicAdd(dst + 1, s1); }
                        s0 = 0.f; s1 = 0.f; bcur = b;
                    }
                    unsigned v = *(const unsigned*)(ew + r * 136 + lane * 2);
                    s0 += b2f((unsigned short)v);
                    s1 += b2f((unsigned short)(v >> 16));
                }
            }
            if (sub == 1) {
                bool interior = (bcur * NPB >= R0) && ((bcur + 1) * NPB <= R0 + 64);
                float* dst = sumB + (size_t)bcur * 128 + 2 * lane;
                if (interior) { dst[0] = s0; dst[1] = s1; }
                else { atomicAdd(dst, s0); atomicAdd(dst + 1, s1); }
            }
        } else {
            // root: row-major global store eR[row][n]; lane row = wrow0+l31
            unsigned short* eRrow = eR + (size_t)(wrow0 + l31) * 128 + 4 * hi;
            #pragma unroll
            for (int nt = 0; nt < 4; ++nt)
                #pragma unroll
                for (int q = 0; q < 4; ++q)
                    *(uint2*)(eRrow + nt * 32 + 8 * q) =
                        (uint2){pvu[nt][2 * q], pvu[nt][2 * q + 1]};
        }
        __asm__ __volatile__("" ::: "memory");   // keep iteration LDS order
    }
}

__global__ __launch_bounds__(1024, 1) void k_mlpE(
    const float* __restrict__ state,
    const unsigned short* __restrict__ W0b_h,
    const unsigned short* __restrict__ W1f_h,
    const unsigned short* __restrict__ Mf_h, unsigned short* __restrict__ tR_h,
    float* __restrict__ shB,
    const unsigned short* __restrict__ W0b_o,
    const unsigned short* __restrict__ W1f_o,
    const unsigned short* __restrict__ Mf_o, unsigned short* __restrict__ tR_o,
    float* __restrict__ soB,
    const unsigned short* __restrict__ W0b_r,
    const unsigned short* __restrict__ W1f_r,
    unsigned short* __restrict__ eR)
{
    __shared__ __align__(16) char smem[SM_SZ];
    int bid = blockIdx.x;
    if (bid < 160)
        mlp_blockE<20, 0, 6, 7, true>(bid * 1024, state, W0b_h, W1f_h,
                                      Mf_h, tR_h, shB, nullptr, smem);
    else if (bid < 240)
        mlp_blockE<10, 20, 6, 7, true>((bid - 160) * 1024, state, W0b_o, W1f_o,
                                       Mf_o, tR_o, soB, nullptr, smem);
    else
        mlp_blockE<1, 0, 0, 6, false>((bid - 240) * 1024, state, W0b_r, W1f_r,
                                      nullptr, nullptr, nullptr, eR, smem);
}

// ---------------------------------------------------------------------------
// k_tail (R18): back to 16 real b's per block x 512 blocks (R16/R17's
// 8-b split doubled total work -- regression). Occupancy gain now comes from
// 8 WAVES per block (512 threads) at the SAME total work: phase-2's 6 nt and
// phase-4/6's 8 nt go one-per-wave, phase-5's 16 nt two-per-wave, phase-3's
// 512 scan items one-per-thread. 2 blocks/CU x 8 waves = 16 waves/CU (was 8).
// LDS 33KB x 2 = 66KB/CU.
// ---------------------------------------------------------------------------
__global__ __launch_bounds__(512, 4) void k_tail(
    const unsigned short* __restrict__ eR,
    const float* __restrict__ shB, const float* __restrict__ soB,
    const unsigned short* __restrict__ tR_h, const unsigned short* __restrict__ tR_o,
    const unsigned short* __restrict__ Wcatf, const float* __restrict__ bcat,
    const unsigned short* __restrict__ Wc2f, const float* __restrict__ bc2,
    const unsigned short* __restrict__ vW0f, const float* __restrict__ vb0,
    const unsigned short* __restrict__ vW1f, const float* __restrict__ vb1,
    const float* __restrict__ vW2, const float* __restrict__ vb2,
    float* __restrict__ out)
{
    __shared__ __align__(16) char sm[33024];
    unsigned short* Ub  = (unsigned short*)(sm);          // [16][400]
    unsigned short* V1b = (unsigned short*)(sm);          // alias  [16][264]
    unsigned short* Vb  = (unsigned short*)(sm + 12800);  // [16][104]
    float* chL          = (float*)(sm + 16128);           // [16][32]
    float* coL          = (float*)(sm + 18176);           // [16][32]
    unsigned short* Hb  = (unsigned short*)(sm + 20224);  // [16][136]
    float* V2b          = (float*)(sm + 24576);           // [16][132]

    const int t = threadIdx.x, lane = t & 63, w = t >> 6;   // w = 0..7
    const int l15 = lane & 15, quad = lane >> 4;
    const int b0 = blockIdx.x * 16;
    const int rowb = quad * 4;

    // ---- phase 1: stage U = [er | sh | so], 16 b's, 512 threads ----
    if (t < 256) {
        int b = t >> 4, q = t & 15;
        ((uint4*)(Ub + b * 400))[q] = ((const uint4*)(eR + (size_t)(b0 + b) * 128))[q];
    }
    #pragma unroll
    for (int rep = 0; rep < 2; ++rep) {
        int idx = t + rep * 512;              // 1024 slots = 16 b x 64 float4
        int b = idx >> 6, q = idx & 63;
        float4 v = (q < 32)
            ? *(const float4*)(shB + (size_t)(b0 + b) * 128 + q * 4)
            : *(const float4*)(soB + (size_t)(b0 + b) * 128 + (q - 32) * 4);
        *(uint2*)(Ub + b * 400 + 128 + q * 4) =
            (uint2){pack2n(v.x, v.y), pack2n(v.z, v.w)};
    }
    __syncthreads();

    // ---- phase 2: U-MFMA (unswapped, verified): xr / ch / co; 1 nt/wave ----
    if (w < 6) {
        const int nt = w;
        float bias = bcat[nt * 16 + l15];
        f32x4 acc = {bias, bias, bias, bias};
        #pragma unroll
        for (int ks = 0; ks < 12; ++ks) {
            bf16x8 a = *(const bf16x8*)(Ub + l15 * 400 + ks * 32 + quad * 8);
            bf16x8 bw = *(const bf16x8*)(Wcatf + ((ks * 6 + nt) * 64 + lane) * 8);
            acc = __builtin_amdgcn_mfma_f32_16x16x32_bf16(a, bw, acc, 0, 0, 0);
        }
        int n = nt * 16 + l15;
        #pragma unroll
        for (int reg = 0; reg < 4; ++reg) {
            float v = acc[reg];
            int b = rowb + reg;
            if (n < 32)      Vb[b * 104 + n] = f2b(fmaxf(v, 0.f));
            else if (n < 64) chL[b * 32 + (n - 32)] = v;
            else             coL[b * 32 + (n - 64)] = v;
        }
    }
    __syncthreads();

    // ---- phase 3: t-scan (row-major tR, coalesced): 512 items, 1/thread ----
    {
        int b = t >> 5, m = t & 31;           // 512 threads = 16 b x 32 m
        float ch = chL[b * 32 + m];
        const unsigned short* p = tR_h + (size_t)(b0 + b) * 20 * 32 + m;
        float s = 0.f;
        #pragma unroll
        for (int n = 0; n < 20; ++n) s += fmaxf(ch + b2f(p[n * 32]), 0.f);
        Vb[b * 104 + 32 + m] = f2b(s);
        float co = coL[b * 32 + m];
        const unsigned short* p2 = tR_o + (size_t)(b0 + b) * 10 * 32 + m;
        float s2 = 0.f;
        #pragma unroll
        for (int n = 0; n < 10; ++n) s2 += fmaxf(co + b2f(p2[n * 32]), 0.f);
        Vb[b * 104 + 64 + m] = f2b(s2);
    }
    __syncthreads();

    // ---- phase 4: c2 (N=128, 1 nt per wave) ----
    {
        const int nt = w;
        float bias = bc2[nt * 16 + l15];
        f32x4 acc = {bias, bias, bias, bias};
        #pragma unroll
        for (int ks = 0; ks < 3; ++ks) {
            bf16x8 a = *(const bf16x8*)(Vb + l15 * 104 + ks * 32 + quad * 8);
            bf16x8 bw = *(const bf16x8*)(Wc2f + ((ks * 8 + nt) * 64 + lane) * 8);
            acc = __builtin_amdgcn_mfma_f32_16x16x32_bf16(a, bw, acc, 0, 0, 0);
        }
        #pragma unroll
        for (int reg = 0; reg < 4; ++reg)
            Hb[(rowb + reg) * 136 + nt * 16 + l15] = f2b(fmaxf(acc[reg], 0.f));
    }
    __syncthreads();

    // ---- phase 5: v1 (N=256, 2 nt per wave; V1b aliases dead Ub) ----
    {
        f32x4 acc[2];
        #pragma unroll
        for (int q = 0; q < 2; ++q) {
            int nt = w + q * 8;
            float bias = vb0[nt * 16 + l15];
            acc[q] = (f32x4){bias, bias, bias, bias};
        }
        #pragma unroll
        for (int ks = 0; ks < 4; ++ks) {
            bf16x8 a = *(const bf16x8*)(Hb + l15 * 136 + ks * 32 + quad * 8);
            #pragma unroll
            for (int q = 0; q < 2; ++q) {
                int nt = w + q * 8;
                bf16x8 bw = *(const bf16x8*)(vW0f + ((ks * 16 + nt) * 64 + lane) * 8);
                acc[q] = __builtin_amdgcn_mfma_f32_16x16x32_bf16(a, bw, acc[q], 0, 0, 0);
            }
        }
        __syncthreads();   // order Ub reads (done) vs V1b writes
        #pragma unroll
        for (int q = 0; q < 2; ++q) {
            int nt = w + q * 8;
            #pragma unroll
            for (int reg = 0; reg < 4; ++reg)
                V1b[(rowb + reg) * 264 + nt * 16 + l15] = f2b(fmaxf(acc[q][reg], 0.f));
        }
    }
    __syncthreads();

    // ---- phase 6: v2 (N=128, 1 nt per wave) ----
    {
        const int nt = w;
        float bias = vb1[nt * 16 + l15];
        f32x4 acc = {bias, bias, bias, bias};
        #pragma unroll
        for (int ks = 0; ks < 8; ++ks) {
            bf16x8 a = *(const bf16x8*)(V1b + l15 * 264 + ks * 32 + quad * 8);
            bf16x8 bw = *(const bf16x8*)(vW1f + ((ks * 8 + nt) * 64 + lane) * 8);
            acc = __builtin_amdgcn_mfma_f32_16x16x32_bf16(a, bw, acc, 0, 0, 0);
        }
        #pragma unroll
        for (int reg = 0; reg < 4; ++reg)
            V2b[(rowb + reg) * 132 + nt * 16 + l15] = fmaxf(acc[reg], 0.f);
    }
    __syncthreads();

    // ---- phase 7: v3, 8 threads per b + shuffle reduce ----
    if (t < 128) {
        int b = t >> 3, j = t & 7;
        float v = 0.f;
        #pragma unroll
        for (int k = 0; k < 16; ++k)
            v = fmaf(V2b[b * 132 + j * 16 + k], vW2[j * 16 + k], v);
        v += __shfl_down(v, 4, 8);
        v += __shfl_down(v, 2, 8);
        v += __shfl_down(v, 1, 8);
        if (j == 0) out[b0 + b] = v + vb2[0];
    }
}

// ---------------------------------------------------------------------------
extern "C" void kernel_launch(void* const* d_in, const int* in_sizes, int n_in,
                              void* d_out, int out_size, void* d_ws, size_t ws_size,
                              hipStream_t stream)
{
    const float* state   = (const float*)d_in[0];
    const float* wr_W0   = (const float*)d_in[2];
    const float* wr_b0   = (const float*)d_in[3];
    const float* wr_W1   = (const float*)d_in[4];
    const float* wr_b1   = (const float*)d_in[5];
    const float* wh_W0   = (const float*)d_in[6];
    const float* wh_b0   = (const float*)d_in[7];
    const float* wh_W1   = (const float*)d_in[8];
    const float* wh_b1   = (const float*)d_in[9];
    const float* wo_W0   = (const float*)d_in[10];
    const float* wo_b0   = (const float*)d_in[11];
    const float* wo_W1   = (const float*)d_in[12];
    const float* wo_b1   = (const float*)d_in[13];
    const float* c1_relW = (const float*)d_in[14];
    const float* c1_relb = (const float*)d_in[15];
    const float* c1_rootW= (const float*)d_in[16];
    const float* c2_relW = (const float*)d_in[17];
    const float* c2_relb = (const float*)d_in[18];
    const float* c2_rootW= (const float*)d_in[19];
    const float* v_W0    = (const float*)d_in[20];
    const float* v_b0    = (const float*)d_in[21];
    const float* v_W1    = (const float*)d_in[22];
    const float* v_b1    = (const float*)d_in[23];
    const float* v_W2    = (const float*)d_in[24];
    const float* v_b2    = (const float*)d_in[25];

    char* ws = (char*)d_ws;
    size_t off = 0;
    auto alloc = [&](size_t bytes) -> char* {
        char* p = ws + off;
        off = (off + bytes + 255) & ~(size_t)255;
        return p;
    };
    float* shB  = (float*)alloc((size_t)BATCH * 128 * 4);          // b-major sums
    float* soB  = (float*)alloc((size_t)BATCH * 128 * 4);          // contiguous with shB
    unsigned short* tR_h = (unsigned short*)alloc((size_t)163840 * 32 * 2);  // row-major
    unsigned short* tR_o = (unsigned short*)alloc((size_t)81920 * 32 * 2);   // row-major
    unsigned short* eR   = (unsigned short*)alloc((size_t)BATCH * 128 * 2);
    float* bcat = (float*)alloc(96 * 4);
    float* bc2  = (float*)alloc(128 * 4);
    unsigned short* W0b_h = (unsigned short*)alloc(4096 * 2);
    unsigned short* W0b_o = (unsigned short*)alloc(4096 * 2);
    unsigned short* W0b_r = (unsigned short*)alloc(4096 * 2);
    unsigned short* W1f_h = (unsigned short*)alloc(34816 * 2);
    unsigned short* W1f_o = (unsigned short*)alloc(34816 * 2);
    unsigned short* W1f_r = (unsigned short*)alloc(34816 * 2);
    unsigned short* Mf_h  = (unsigned short*)alloc(4096 * 2);
    unsigned short* Mf_o  = (unsigned short*)alloc(4096 * 2);
    unsigned short* Wcatf = (unsigned short*)alloc(36864 * 2);
    unsigned short* Wc2f  = (unsigned short*)alloc(12288 * 2);
    unsigned short* vW0f  = (unsigned short*)alloc(32768 * 2);
    unsigned short* vW1f  = (unsigned short*)alloc(32768 * 2);
    (void)ws_size; (void)in_sizes; (void)n_in; (void)out_size;

    hipMemsetAsync(shB, 0, (size_t)2 * BATCH * 128 * 4, stream);

    k_prep<<<256, 256, 0, stream>>>(c1_relW, c1_relb, c1_rootW, c2_relW, c2_relb, c2_rootW,
                                    wh_W0, wh_W1, wo_W0, wo_W1, wr_W0, wr_W1, v_W0, v_W1,
                                    wh_b0, wo_b0, wr_b0, wh_b1, wo_b1, wr_b1,
                                    bcat, bc2, W0b_h, W0b_o, W0b_r, W1f_h, W1f_o, W1f_r,
                                    Mf_h, Mf_o, Wcatf, Wc2f, vW0f, vW1f);

    k_mlpE<<<248, 1024, 0, stream>>>(state,
                                     W0b_h, W1f_h, Mf_h, tR_h, shB,
                                     W0b_o, W1f_o, Mf_o, tR_o, soB,
                                     W0b_r, W1f_r, eR);

    k_tail<<<512, 512, 0, stream>>>(eR, shB, soB, tR_h, tR_o,
                                    Wcatf, bcat, Wc2f, bc2, vW0f, v_b0, vW1f, v_b1,
                                    v_W2, v_b2, (float*)d_out);
}

// Round 9
// 153.866 us; speedup vs baseline: 1.0495x; 1.0292x over previous
//
#include <hip/hip_runtime.h>
#include <hip/hip_bf16.h>
#include <stdint.h>

#define BATCH 8192
#define NSTATE 30
#define DIN 13
#define E1 256
#define E2 128

typedef short bf16x8 __attribute__((ext_vector_type(8)));
typedef float f32x4 __attribute__((ext_vector_type(4)));
typedef float f32x16 __attribute__((ext_vector_type(16)));
typedef __bf16 bf16x2_t __attribute__((ext_vector_type(2)));

// f32 -> bf16 bits, round-to-nearest-even (native cast -> v_cvt_pk_bf16_f32)
__device__ __forceinline__ unsigned short f2b(float f) {
    return __builtin_bit_cast(unsigned short, (__bf16)f);
}
__device__ __forceinline__ float b2f(unsigned short b) {
    return __uint_as_float((unsigned)b << 16);
}
__device__ __forceinline__ unsigned pack2(float a, float b) {     // relu+pack
    bf16x2_t v = {(__bf16)fmaxf(a, 0.f), (__bf16)fmaxf(b, 0.f)};
    return __builtin_bit_cast(unsigned, v);
}
__device__ __forceinline__ unsigned pack2n(float a, float b) {    // pack only
    bf16x2_t v = {(__bf16)a, (__bf16)b};
    return __builtin_bit_cast(unsigned, v);
}

// combined conv1 weight values (derived R1, verified)
__device__ __forceinline__ float wcat_val(int k, int m, const float* relW, const float* rootW) {
    int part = k >> 7, c = k & 127, grp = m >> 5, mm = m & 31;
    int off = c * 32 + mm;
    if (part == 0) return (grp == 0) ? rootW[4096 + off] + rootW[8192 + off]
                        : (grp == 1) ? relW[off] : relW[3*4096 + off];
    if (part == 1) return (grp == 0) ? relW[1*4096 + off]
                        : (grp == 1) ? relW[6*4096 + off] : relW[5*4096 + off];
    return (grp == 0) ? relW[2*4096 + off]
         : (grp == 1) ? relW[4*4096 + off] : relW[7*4096 + off];
}
__device__ __forceinline__ float wc2_val(int k, int n, const float* relW, const float* rootW) {
    int grp = k >> 5, kk = k & 31;
    int off = kk * 128 + n;
    if (grp == 0) return rootW[4096 + off] + rootW[8192 + off];
    if (grp == 1) return relW[4096 + off];
    return relW[8192 + off];
}

// ---------------------------------------------------------------------------
// k_prep (R15): fragment tables for mfma_f32_32x32x16_bf16 in k_mlpE.
// 32x32x16 operand decode (verified on-HW by R15's pass):
//   A/B: lane l holds m/n = l&31, k = (l>>5)*8 + j  (j = bf16 slot 0..7)
//   C/D: col = lane&31, row = (reg&3) + 8*(reg>>2) + 4*(lane>>5)
// W0b:  [nt_h(8)][l][j] : W0 row j (j==INDIM -> b0, bias-in-MFMA), col 32nt+l31.
// W1f:  [ks(17)][nt(4)][l][j] : h-dim permuted so the L2 B-operand equals the
//       packed L1 accumulator registers (same-lane); ks==16 = b1 bias slice.
// Mf:   [kt(8)][l][j] : e-dim permuted the same way (e from L2 acc registers).
// k_tail tables (Wcatf/Wc2f/vW0f/vW1f, 16x16x32 layout) unchanged.
// ---------------------------------------------------------------------------
__global__ void k_prep(const float* __restrict__ c1_relW, const float* __restrict__ c1_relb,
                       const float* __restrict__ c1_rootW,
                       const float* __restrict__ c2_relW, const float* __restrict__ c2_relb,
                       const float* __restrict__ c2_rootW,
                       const float* __restrict__ wh_W0, const float* __restrict__ wh_W1,
                       const float* __restrict__ wo_W0, const float* __restrict__ wo_W1,
                       const float* __restrict__ wr_W0, const float* __restrict__ wr_W1,
                       const float* __restrict__ v_W0, const float* __restrict__ v_W1,
                       const float* __restrict__ b0h, const float* __restrict__ b0o,
                       const float* __restrict__ b0r,
                       const float* __restrict__ b1h, const float* __restrict__ b1o,
                       const float* __restrict__ b1r,
                       float* __restrict__ bcat, float* __restrict__ bc2,
                       unsigned short* __restrict__ W0b_h, unsigned short* __restrict__ W0b_o,
                       unsigned short* __restrict__ W0b_r,
                       unsigned short* __restrict__ W1f_h, unsigned short* __restrict__ W1f_o,
                       unsigned short* __restrict__ W1f_r,
                       unsigned short* __restrict__ Mf_h, unsigned short* __restrict__ Mf_o,
                       unsigned short* __restrict__ Wcatf, unsigned short* __restrict__ Wc2f,
                       unsigned short* __restrict__ vW0f, unsigned short* __restrict__ vW1f)
{
    int gid = blockIdx.x * blockDim.x + threadIdx.x;
    int gsz = gridDim.x * blockDim.x;

    for (int i = gid; i < 96; i += gsz) {
        int grp = i >> 5, mm = i & 31;
        float v;
        if (grp == 0)      v = c1_relb[32 + mm] + c1_relb[64 + mm];
        else if (grp == 1) v = c1_relb[mm] + c1_relb[128 + mm] + c1_relb[192 + mm];
        else               v = c1_relb[96 + mm] + c1_relb[160 + mm] + c1_relb[224 + mm];
        bcat[i] = v;
    }
    for (int i = gid; i < 128; i += gsz) bc2[i] = c2_relb[128 + i] + c2_relb[256 + i];

    // W0 fragments (32x32x16): 8 nt_h tiles x 64 lanes x 8 slots
    for (int i = gid; i < 4096; i += gsz) {
        int j = i & 7, l = (i >> 3) & 63, nh = i >> 9;
        int col = nh * 32 + (l & 31);
        unsigned short vh = 0, vo = 0, vr = 0;
        if (l < 32) {
            vh = (j < 7) ? f2b(wh_W0[j * 256 + col]) : f2b(b0h[col]);
            vo = (j < 7) ? f2b(wo_W0[j * 256 + col]) : f2b(b0o[col]);
            vr = (j < 6) ? f2b(wr_W0[j * 256 + col])
               : (j == 6) ? f2b(b0r[col]) : (unsigned short)0;
        }
        W0b_h[i] = vh; W0b_o[i] = vo; W0b_r[i] = vr;
    }
    // W1 fragments (32x32x16, permuted h-dim, 17th slice = b1)
    for (int i = gid; i < 34816; i += gsz) {
        int j = i & 7, l = (i >> 3) & 63, rem = i >> 9;
        int nt = rem & 3, ks = rem >> 2;
        int ecol = nt * 32 + (l & 31);
        int hh = l >> 5;
        unsigned short vh, vo, vr;
        if (ks < 16) {
            int r = (ks & 1) * 8 + j;
            int hcol = (ks >> 1) * 32 + (r & 3) + 8 * (r >> 2) + 4 * hh;
            vh = f2b(wh_W1[hcol * 128 + ecol]);
            vo = f2b(wo_W1[hcol * 128 + ecol]);
            vr = f2b(wr_W1[hcol * 128 + ecol]);
        } else {
            bool on = (l < 32) && (j == 0);
            vh = on ? f2b(b1h[ecol]) : (unsigned short)0;
            vo = on ? f2b(b1o[ecol]) : (unsigned short)0;
            vr = on ? f2b(b1r[ecol]) : (unsigned short)0;
        }
        W1f_h[i] = vh; W1f_o[i] = vo; W1f_r[i] = vr;
    }
    // Mf fragments (32x32x16, permuted e-dim)
    for (int i = gid; i < 4096; i += gsz) {
        int j = i & 7, l = (i >> 3) & 63, kt = i >> 9;
        int hh = l >> 5, s = kt & 1, r = s * 8 + j;
        int ecol = (kt >> 1) * 32 + (r & 3) + 8 * (r >> 2) + 4 * hh;
        int tcol = l & 31;
        int i0 = ecol * 32 + tcol;
        Mf_h[i] = f2b(c1_rootW[i0] + c1_rootW[4*4096 + i0] + c1_rootW[6*4096 + i0] - c1_relW[6*4096 + i0]);
        Mf_o[i] = f2b(c1_rootW[3*4096 + i0] + c1_rootW[5*4096 + i0] + c1_rootW[7*4096 + i0] - c1_relW[7*4096 + i0]);
    }
    // ---- k_tail tables (16x16x32 layout, unchanged) ----
    for (int i = gid; i < 36864; i += gsz) {
        int j = i & 7, l = (i >> 3) & 63, rem = i >> 9;
        int nt = rem % 6, ks = rem / 6;
        int k = ks * 32 + (l >> 4) * 8 + j;
        int n = nt * 16 + (l & 15);
        Wcatf[i] = f2b(wcat_val(k, n, c1_relW, c1_rootW));
    }
    for (int i = gid; i < 12288; i += gsz) {
        int j = i & 7, l = (i >> 3) & 63, rem = i >> 9;
        int nt = rem & 7, ks = rem >> 3;
        int k = ks * 32 + (l >> 4) * 8 + j;
        int n = nt * 16 + (l & 15);
        Wc2f[i] = f2b(wc2_val(k, n, c2_relW, c2_rootW));
    }
    for (int i = gid; i < 32768; i += gsz) {
        int j = i & 7, l = (i >> 3) & 63, rem = i >> 9;
        int nt = rem & 15, ks = rem >> 4;
        int k = ks * 32 + (l >> 4) * 8 + j;
        int n = nt * 16 + (l & 15);
        vW0f[i] = f2b(v_W0[k * 256 + n]);
    }
    for (int i = gid; i < 32768; i += gsz) {
        int j = i & 7, l = (i >> 3) & 63, rem = i >> 9;
        int nt = rem & 7, ks = rem >> 3;
        int k = ks * 32 + (l >> 4) * 8 + j;
        int n = nt * 16 + (l & 15);
        vW1f[i] = f2b(v_W1[k * 128 + n]);
    }
}

// ---------------------------------------------------------------------------
// mlp_blockE (R15): 32x32x16-MFMA register-direct dataflow. One 32-row sub;
// W1 LDS fragments read once per 32 rows; L1 acc -> pack -> L2 B-operand and
// L2 acc -> pack -> t-MFMA B-operand entirely in registers (permuted tables).
// b1 enters as W1 K-slice 16 against a constant ones-fragment.
// LDS: W0s@0 8K | Mfs@8K 8K | W1s@16K 68K | ew@86016 16x4352 = 152K total.
// ---------------------------------------------------------------------------
#define SM_W0   0
#define SM_MF   8192
#define SM_W1   16384
#define SM_HS   86016
#define SM_SZ   (86016 + 16 * 16 * 136 * 2)

template<int NPB, int NODE0, int INOFF, int INDIM, bool TAIL>
__device__ __forceinline__ void mlp_blockE(
    int blkrow0, const float* __restrict__ state,
    const unsigned short* __restrict__ W0b_g,
    const unsigned short* __restrict__ W1f_g,
    const unsigned short* __restrict__ Mf_g,
    unsigned short* __restrict__ tR, float* __restrict__ sumB,
    unsigned short* __restrict__ eR, char* smem)
{
    unsigned short* W0s = (unsigned short*)(smem + SM_W0);
    unsigned short* Mfs = (unsigned short*)(smem + SM_MF);
    unsigned short* W1s = (unsigned short*)(smem + SM_W1);

    const int t = threadIdx.x;
    const int lane = t & 63;
    const int w = t >> 6;
    const int l31 = lane & 31;
    const int hi = lane >> 5;
    const int R0 = blkrow0 + w * 64;      // this wave's 64 contiguous rows
    unsigned short* ew = (unsigned short*)(smem + SM_HS) + w * (16 * 136); // [16][136]

    // ---- one-time staging (1024 threads) ----
    if (t < 512) ((uint4*)W0s)[t] = ((const uint4*)W0b_g)[t];
    if constexpr (TAIL) {
        if (t >= 512) ((uint4*)Mfs)[t - 512] = ((const uint4*)Mf_g)[t - 512];
    }
    #pragma unroll
    for (int i = 0; i < 4; ++i)
        ((uint4*)W1s)[t + 1024 * i] = ((const uint4*)W1f_g)[t + 1024 * i];
    if (t < 256) ((uint4*)W1s)[4096 + t] = ((const uint4*)W1f_g)[4096 + t];
    __syncthreads();   // the ONLY block-wide barrier

    // constant ones-fragment for the b1 bias K-slice (k-slot 0 on lo lanes)
    bf16x8 bones = {};
    if (lane < 32) bones[0] = (short)0x3F80;

    float s0 = 0.f, s1 = 0.f;
    int bcur = R0 / NPB;

    // ---- X pipeline: lanes 0..31 own rows l31; prefetch next sub ----
    float xf[INDIM];
    if (lane < 32) {
        int grow = R0 + l31;
        int b = grow / NPB;
        int n = grow - b * NPB + NODE0;
        const float* xp = state + ((size_t)b * NSTATE + n) * DIN + INOFF;
        #pragma unroll
        for (int j = 0; j < INDIM; ++j) xf[j] = xp[j];
    }

    for (int sub = 0; sub < 2; ++sub) {
        const int wrow0 = R0 + sub * 32;

        bf16x8 bx = {};
        if (lane < 32) {
            #pragma unroll
            for (int j = 0; j < INDIM; ++j) bx[j] = (short)f2b(xf[j]);
            bx[INDIM] = (short)0x3F80;   // multiplies the b0 A-slot
        }
        if (sub < 1 && lane < 32) {
            int grow = wrow0 + 32 + l31;
            int b = grow / NPB;
            int n = grow - b * NPB + NODE0;
            const float* xp = state + ((size_t)b * NSTATE + n) * DIN + INOFF;
            #pragma unroll
            for (int j = 0; j < INDIM; ++j) xf[j] = xp[j];
        }

        // ---- L1 + L2 interleaved: per h-tile nh, one 32x32 L1 MFMA makes
        // h cols 32nh..+31; pack regs 0..7 / 8..15 into the two K-slice
        // B-fragments and immediately burn them against 4 e-col tiles. ----
        f32x16 acc[4];
        #pragma unroll
        for (int nt = 0; nt < 4; ++nt) { f32x16 z = {}; acc[nt] = z; }
        #pragma unroll
        for (int nh = 0; nh < 8; ++nh) {
            bf16x8 aw0 = *(const bf16x8*)(W0s + (nh * 64 + lane) * 8);
            f32x16 z = {};
            f32x16 a1 = __builtin_amdgcn_mfma_f32_32x32x16_bf16(aw0, bx, z, 0, 0, 0);
            uint4 ua, ub;
            ua.x = pack2(a1[0], a1[1]);   ua.y = pack2(a1[2], a1[3]);
            ua.z = pack2(a1[4], a1[5]);   ua.w = pack2(a1[6], a1[7]);
            ub.x = pack2(a1[8], a1[9]);   ub.y = pack2(a1[10], a1[11]);
            ub.z = pack2(a1[12], a1[13]); ub.w = pack2(a1[14], a1[15]);
            bf16x8 bhA = __builtin_bit_cast(bf16x8, ua);
            bf16x8 bhB = __builtin_bit_cast(bf16x8, ub);
            #pragma unroll
            for (int nt = 0; nt < 4; ++nt) {
                bf16x8 aw = *(const bf16x8*)(W1s + (((2 * nh) * 4 + nt) * 64 + lane) * 8);
                acc[nt] = __builtin_amdgcn_mfma_f32_32x32x16_bf16(aw, bhA, acc[nt], 0, 0, 0);
            }
            #pragma unroll
            for (int nt = 0; nt < 4; ++nt) {
                bf16x8 aw = *(const bf16x8*)(W1s + (((2 * nh + 1) * 4 + nt) * 64 + lane) * 8);
                acc[nt] = __builtin_amdgcn_mfma_f32_32x32x16_bf16(aw, bhB, acc[nt], 0, 0, 0);
            }
        }
        // b1 bias K-slice
        #pragma unroll
        for (int nt = 0; nt < 4; ++nt) {
            bf16x8 aw = *(const bf16x8*)(W1s + ((64 + nt) * 64 + lane) * 8);
            acc[nt] = __builtin_amdgcn_mfma_f32_32x32x16_bf16(aw, bones, acc[nt], 0, 0, 0);
        }

        // relu+pack e once; feeds t-MFMA B, ew stores, eR stores
        unsigned pvu[4][8];
        #pragma unroll
        for (int nt = 0; nt < 4; ++nt)
            #pragma unroll
            for (int p = 0; p < 8; ++p)
                pvu[nt][p] = pack2(acc[nt][2 * p], acc[nt][2 * p + 1]);

        if constexpr (TAIL) {
            // t = e @ M : A=Mf (permuted e-dim), B=e from REGISTERS
            f32x16 tacc = {};
            #pragma unroll
            for (int kt = 0; kt < 8; ++kt) {
                const int nt = kt >> 1, s = kt & 1;
                uint4 ua = {pvu[nt][4 * s], pvu[nt][4 * s + 1],
                            pvu[nt][4 * s + 2], pvu[nt][4 * s + 3]};
                bf16x8 ae = __builtin_bit_cast(bf16x8, ua);
                bf16x8 bm = *(const bf16x8*)(Mfs + (kt * 64 + lane) * 8);
                tacc = __builtin_amdgcn_mfma_f32_32x32x16_bf16(bm, ae, tacc, 0, 0, 0);
            }
            // tR row-major store: lane's row = wrow0+l31; 16 t-cols per lane
            {
                unsigned short* tRrow = tR + (size_t)(wrow0 + l31) * 32 + 4 * hi;
                #pragma unroll
                for (int q = 0; q < 4; ++q) {
                    uint2 tv = {pack2n(tacc[4 * q], tacc[4 * q + 1]),
                                pack2n(tacc[4 * q + 2], tacc[4 * q + 3])};
                    *(uint2*)(tRrow + 8 * q) = tv;
                }
            }
            // ew + scan in two 16-row half-passes (preserves old scan format)
            #pragma unroll
            for (int half = 0; half < 2; ++half) {
                __asm__ __volatile__("s_waitcnt lgkmcnt(0)" ::: "memory");
                if ((l31 >> 4) == half) {
                    unsigned short* er = ew + (l31 & 15) * 136 + 4 * hi;
                    #pragma unroll
                    for (int nt = 0; nt < 4; ++nt)
                        #pragma unroll
                        for (int q = 0; q < 4; ++q)
                            *(uint2*)(er + nt * 32 + 8 * q) =
                                (uint2){pvu[nt][2 * q], pvu[nt][2 * q + 1]};
                }
                const int grow0 = wrow0 + half * 16;
                #pragma unroll
                for (int r = 0; r < 16; ++r) {
                    int b = (grow0 + r) / NPB;
                    if (b != bcur) {
                        bool interior = (bcur * NPB >= R0) && ((bcur + 1) * NPB <= R0 + 64);
                        float* dst = sumB + (size_t)bcur * 128 + 2 * lane;
                        if (interior) { dst[0] = s0; dst[1] = s1; }
                        else { atomicAdd(dst, s0); atomicAdd(dst + 1, s1); }
                        s0 = 0.f; s1 = 0.f; bcur = b;
                    }
                    unsigned v = *(const unsigned*)(ew + r * 136 + lane * 2);
                    s0 += b2f((unsigned short)v);
                    s1 += b2f((unsigned short)(v >> 16));
                }
            }
            if (sub == 1) {
                bool interior = (bcur * NPB >= R0) && ((bcur + 1) * NPB <= R0 + 64);
                float* dst = sumB + (size_t)bcur * 128 + 2 * lane;
                if (interior) { dst[0] = s0; dst[1] = s1; }
                else { atomicAdd(dst, s0); atomicAdd(dst + 1, s1); }
            }
        } else {
            // root: row-major global store eR[row][n]; lane row = wrow0+l31
            unsigned short* eRrow = eR + (size_t)(wrow0 + l31) * 128 + 4 * hi;
            #pragma unroll
            for (int nt = 0; nt < 4; ++nt)
                #pragma unroll
                for (int q = 0; q < 4; ++q)
                    *(uint2*)(eRrow + nt * 32 + 8 * q) =
                        (uint2){pvu[nt][2 * q], pvu[nt][2 * q + 1]};
        }
        __asm__ __volatile__("" ::: "memory");   // keep iteration LDS order
    }
}

__global__ __launch_bounds__(1024, 1) void k_mlpE(
    const float* __restrict__ state,
    const unsigned short* __restrict__ W0b_h,
    const unsigned short* __restrict__ W1f_h,
    const unsigned short* __restrict__ Mf_h, unsigned short* __restrict__ tR_h,
    float* __restrict__ shB,
    const unsigned short* __restrict__ W0b_o,
    const unsigned short* __restrict__ W1f_o,
    const unsigned short* __restrict__ Mf_o, unsigned short* __restrict__ tR_o,
    float* __restrict__ soB,
    const unsigned short* __restrict__ W0b_r,
    const unsigned short* __restrict__ W1f_r,
    unsigned short* __restrict__ eR)
{
    __shared__ __align__(16) char smem[SM_SZ];
    int bid = blockIdx.x;
    if (bid < 160)
        mlp_blockE<20, 0, 6, 7, true>(bid * 1024, state, W0b_h, W1f_h,
                                      Mf_h, tR_h, shB, nullptr, smem);
    else if (bid < 240)
        mlp_blockE<10, 20, 6, 7, true>((bid - 160) * 1024, state, W0b_o, W1f_o,
                                       Mf_o, tR_o, soB, nullptr, smem);
    else
        mlp_blockE<1, 0, 0, 6, false>((bid - 240) * 1024, state, W0b_r, W1f_r,
                                      nullptr, nullptr, nullptr, eR, smem);
}

// ---------------------------------------------------------------------------
// k_tail (R15 champion version): FUSED u2 + sM + v, 16 b's per block,
// 512 blocks (2 blocks/CU). R16-R18 alternatives (8-b split, 8-wave split)
// both regressed or were null: the kernel is bound by its serial 7-phase
// barrier chain, not wave occupancy. Keeping the verified 4-wave form.
// LDS 33KB: Ub[16][400] (V1b aliases) | Vb[16][104] | chL/coL | Hb | V2b
// ---------------------------------------------------------------------------
__global__ __launch_bounds__(256, 2) void k_tail(
    const unsigned short* __restrict__ eR,
    const float* __restrict__ shB, const float* __restrict__ soB,
    const unsigned short* __restrict__ tR_h, const unsigned short* __restrict__ tR_o,
    const unsigned short* __restrict__ Wcatf, const float* __restrict__ bcat,
    const unsigned short* __restrict__ Wc2f, const float* __restrict__ bc2,
    const unsigned short* __restrict__ vW0f, const float* __restrict__ vb0,
    const unsigned short* __restrict__ vW1f, const float* __restrict__ vb1,
    const float* __restrict__ vW2, const float* __restrict__ vb2,
    float* __restrict__ out)
{
    __shared__ __align__(16) char sm[33024];
    unsigned short* Ub  = (unsigned short*)(sm);          // [16][400]
    unsigned short* V1b = (unsigned short*)(sm);          // alias  [16][264]
    unsigned short* Vb  = (unsigned short*)(sm + 12800);  // [16][104]
    float* chL          = (float*)(sm + 16128);           // [16][32]
    float* coL          = (float*)(sm + 18176);           // [16][32]
    unsigned short* Hb  = (unsigned short*)(sm + 20224);  // [16][136]
    float* V2b          = (float*)(sm + 24576);           // [16][132]

    const int t = threadIdx.x, lane = t & 63, w = t >> 6;
    const int l15 = lane & 15, quad = lane >> 4;
    const int b0 = blockIdx.x * 16;
    const int rowb = quad * 4;

    // ---- phase 1: stage U = [er | sh | so] ----
    {
        int b = t >> 4, q = t & 15;
        ((uint4*)(Ub + b * 400))[q] = ((const uint4*)(eR + (size_t)(b0 + b) * 128))[q];
    }
    for (int idx = t; idx < 4096; idx += 256) {
        int b = idx >> 8, kk = idx & 255;
        float v = (kk < 128) ? shB[(size_t)(b0 + b) * 128 + kk]
                             : soB[(size_t)(b0 + b) * 128 + kk - 128];
        Ub[b * 400 + 128 + kk] = f2b(v);
    }
    __syncthreads();

    // ---- phase 2: U-MFMA (unswapped, verified): xr / ch / co ----
    for (int nt = w; nt < 6; nt += 4) {
        float bias = bcat[nt * 16 + l15];
        f32x4 acc = {bias, bias, bias, bias};
        #pragma unroll
        for (int ks = 0; ks < 12; ++ks) {
            bf16x8 a = *(const bf16x8*)(Ub + l15 * 400 + ks * 32 + quad * 8);
            bf16x8 bw = *(const bf16x8*)(Wcatf + ((ks * 6 + nt) * 64 + lane) * 8);
            acc = __builtin_amdgcn_mfma_f32_16x16x32_bf16(a, bw, acc, 0, 0, 0);
        }
        int n = nt * 16 + l15;
        #pragma unroll
        for (int reg = 0; reg < 4; ++reg) {
            float v = acc[reg];
            int b = rowb + reg;
            if (n < 32)      Vb[b * 104 + n] = f2b(fmaxf(v, 0.f));
            else if (n < 64) chL[b * 32 + (n - 32)] = v;
            else             coL[b * 32 + (n - 64)] = v;
        }
    }
    __syncthreads();

    // ---- phase 3: t-scan (row-major tR, coalesced) -> s2h, s2o ----
    for (int idx = t; idx < 512; idx += 256) {
        int b = idx >> 5, m = idx & 31;
        float ch = chL[b * 32 + m];
        const unsigned short* p = tR_h + (size_t)(b0 + b) * 20 * 32 + m;
        float s = 0.f;
        #pragma unroll
        for (int n = 0; n < 20; ++n) s += fmaxf(ch + b2f(p[n * 32]), 0.f);
        Vb[b * 104 + 32 + m] = f2b(s);
        float co = coL[b * 32 + m];
        const unsigned short* p2 = tR_o + (size_t)(b0 + b) * 10 * 32 + m;
        float s2 = 0.f;
        #pragma unroll
        for (int n = 0; n < 10; ++n) s2 += fmaxf(co + b2f(p2[n * 32]), 0.f);
        Vb[b * 104 + 64 + m] = f2b(s2);
    }
    __syncthreads();

    // ---- phase 4: c2 (N=128, 2 nt per wave) ----
    {
        f32x4 acc[2];
        #pragma unroll
        for (int q = 0; q < 2; ++q) {
            int nt = w + q * 4;
            float bias = bc2[nt * 16 + l15];
            acc[q] = (f32x4){bias, bias, bias, bias};
        }
        #pragma unroll
        for (int ks = 0; ks < 3; ++ks) {
            bf16x8 a = *(const bf16x8*)(Vb + l15 * 104 + ks * 32 + quad * 8);
            #pragma unroll
            for (int q = 0; q < 2; ++q) {
                int nt = w + q * 4;
                bf16x8 bw = *(const bf16x8*)(Wc2f + ((ks * 8 + nt) * 64 + lane) * 8);
                acc[q] = __builtin_amdgcn_mfma_f32_16x16x32_bf16(a, bw, acc[q], 0, 0, 0);
            }
        }
        #pragma unroll
        for (int q = 0; q < 2; ++q) {
            int nt = w + q * 4;
            #pragma unroll
            for (int reg = 0; reg < 4; ++reg)
                Hb[(rowb + reg) * 136 + nt * 16 + l15] = f2b(fmaxf(acc[q][reg], 0.f));
        }
    }
    __syncthreads();

    // ---- phase 5: v1 (N=256, 4 nt per wave; V1b aliases dead Ub) ----
    {
        f32x4 acc[4];
        #pragma unroll
        for (int q = 0; q < 4; ++q) {
            int nt = w + q * 4;
            float bias = vb0[nt * 16 + l15];
            acc[q] = (f32x4){bias, bias, bias, bias};
        }
        #pragma unroll
        for (int ks = 0; ks < 4; ++ks) {
            bf16x8 a = *(const bf16x8*)(Hb + l15 * 136 + ks * 32 + quad * 8);
            #pragma unroll
            for (int q = 0; q < 4; ++q) {
                int nt = w + q * 4;
                bf16x8 bw = *(const bf16x8*)(vW0f + ((ks * 16 + nt) * 64 + lane) * 8);
                acc[q] = __builtin_amdgcn_mfma_f32_16x16x32_bf16(a, bw, acc[q], 0, 0, 0);
            }
        }
        __syncthreads();   // Ub reads (phase-2 done long ago) -> safe; order vs writes
        #pragma unroll
        for (int q = 0; q < 4; ++q) {
            int nt = w + q * 4;
            #pragma unroll
            for (int reg = 0; reg < 4; ++reg)
                V1b[(rowb + reg) * 264 + nt * 16 + l15] = f2b(fmaxf(acc[q][reg], 0.f));
        }
    }
    __syncthreads();

    // ---- phase 6: v2 (N=128, 2 nt per wave) ----
    {
        f32x4 acc[2];
        #pragma unroll
        for (int q = 0; q < 2; ++q) {
            int nt = w + q * 4;
            float bias = vb1[nt * 16 + l15];
            acc[q] = (f32x4){bias, bias, bias, bias};
        }
        #pragma unroll
        for (int ks = 0; ks < 8; ++ks) {
            bf16x8 a = *(const bf16x8*)(V1b + l15 * 264 + ks * 32 + quad * 8);
            #pragma unroll
            for (int q = 0; q < 2; ++q) {
                int nt = w + q * 4;
                bf16x8 bw = *(const bf16x8*)(vW1f + ((ks * 8 + nt) * 64 + lane) * 8);
                acc[q] = __builtin_amdgcn_mfma_f32_16x16x32_bf16(a, bw, acc[q], 0, 0, 0);
            }
        }
        #pragma unroll
        for (int q = 0; q < 2; ++q) {
            int nt = w + q * 4;
            #pragma unroll
            for (int reg = 0; reg < 4; ++reg)
                V2b[(rowb + reg) * 132 + nt * 16 + l15] = fmaxf(acc[q][reg], 0.f);
        }
    }
    __syncthreads();

    // ---- phase 7: v3, 8 threads per b + shuffle reduce ----
    if (t < 128) {
        int b = t >> 3, j = t & 7;
        float v = 0.f;
        #pragma unroll
        for (int k = 0; k < 16; ++k)
            v = fmaf(V2b[b * 132 + j * 16 + k], vW2[j * 16 + k], v);
        v += __shfl_down(v, 4, 8);
        v += __shfl_down(v, 2, 8);
        v += __shfl_down(v, 1, 8);
        if (j == 0) out[b0 + b] = v + vb2[0];
    }
}

// ---------------------------------------------------------------------------
extern "C" void kernel_launch(void* const* d_in, const int* in_sizes, int n_in,
                              void* d_out, int out_size, void* d_ws, size_t ws_size,
                              hipStream_t stream)
{
    const float* state   = (const float*)d_in[0];
    const float* wr_W0   = (const float*)d_in[2];
    const float* wr_b0   = (const float*)d_in[3];
    const float* wr_W1   = (const float*)d_in[4];
    const float* wr_b1   = (const float*)d_in[5];
    const float* wh_W0   = (const float*)d_in[6];
    const float* wh_b0   = (const float*)d_in[7];
    const float* wh_W1   = (const float*)d_in[8];
    const float* wh_b1   = (const float*)d_in[9];
    const float* wo_W0   = (const float*)d_in[10];
    const float* wo_b0   = (const float*)d_in[11];
    const float* wo_W1   = (const float*)d_in[12];
    const float* wo_b1   = (const float*)d_in[13];
    const float* c1_relW = (const float*)d_in[14];
    const float* c1_relb = (const float*)d_in[15];
    const float* c1_rootW= (const float*)d_in[16];
    const float* c2_relW = (const float*)d_in[17];
    const float* c2_relb = (const float*)d_in[18];
    const float* c2_rootW= (const float*)d_in[19];
    const float* v_W0    = (const float*)d_in[20];
    const float* v_b0    = (const float*)d_in[21];
    const float* v_W1    = (const float*)d_in[22];
    const float* v_b1    = (const float*)d_in[23];
    const float* v_W2    = (const float*)d_in[24];
    const float* v_b2    = (const float*)d_in[25];

    char* ws = (char*)d_ws;
    size_t off = 0;
    auto alloc = [&](size_t bytes) -> char* {
        char* p = ws + off;
        off = (off + bytes + 255) & ~(size_t)255;
        return p;
    };
    float* shB  = (float*)alloc((size_t)BATCH * 128 * 4);          // b-major sums
    float* soB  = (float*)alloc((size_t)BATCH * 128 * 4);          // contiguous with shB
    unsigned short* tR_h = (unsigned short*)alloc((size_t)163840 * 32 * 2);  // row-major
    unsigned short* tR_o = (unsigned short*)alloc((size_t)81920 * 32 * 2);   // row-major
    unsigned short* eR   = (unsigned short*)alloc((size_t)BATCH * 128 * 2);
    float* bcat = (float*)alloc(96 * 4);
    float* bc2  = (float*)alloc(128 * 4);
    unsigned short* W0b_h = (unsigned short*)alloc(4096 * 2);
    unsigned short* W0b_o = (unsigned short*)alloc(4096 * 2);
    unsigned short* W0b_r = (unsigned short*)alloc(4096 * 2);
    unsigned short* W1f_h = (unsigned short*)alloc(34816 * 2);
    unsigned short* W1f_o = (unsigned short*)alloc(34816 * 2);
    unsigned short* W1f_r = (unsigned short*)alloc(34816 * 2);
    unsigned short* Mf_h  = (unsigned short*)alloc(4096 * 2);
    unsigned short* Mf_o  = (unsigned short*)alloc(4096 * 2);
    unsigned short* Wcatf = (unsigned short*)alloc(36864 * 2);
    unsigned short* Wc2f  = (unsigned short*)alloc(12288 * 2);
    unsigned short* vW0f  = (unsigned short*)alloc(32768 * 2);
    unsigned short* vW1f  = (unsigned short*)alloc(32768 * 2);
    (void)ws_size; (void)in_sizes; (void)n_in; (void)out_size;

    hipMemsetAsync(shB, 0, (size_t)2 * BATCH * 128 * 4, stream);

    k_prep<<<256, 256, 0, stream>>>(c1_relW, c1_relb, c1_rootW, c2_relW, c2_relb, c2_rootW,
                                    wh_W0, wh_W1, wo_W0, wo_W1, wr_W0, wr_W1, v_W0, v_W1,
                                    wh_b0, wo_b0, wr_b0, wh_b1, wo_b1, wr_b1,
                                    bcat, bc2, W0b_h, W0b_o, W0b_r, W1f_h, W1f_o, W1f_r,
                                    Mf_h, Mf_o, Wcatf, Wc2f, vW0f, vW1f);

    k_mlpE<<<248, 1024, 0, stream>>>(state,
                                     W0b_h, W1f_h, Mf_h, tR_h, shB,
                                     W0b_o, W1f_o, Mf_o, tR_o, soB,
                                     W0b_r, W1f_r, eR);

    k_tail<<<512, 256, 0, stream>>>(eR, shB, soB, tR_h, tR_o,
                                    Wcatf, bcat, Wc2f, bc2, vW0f, v_b0, vW1f, v_b1,
                                    v_W2, v_b2, (float*)d_out);
}